// Round 4
// baseline (849.320 us; speedup 1.0000x reference)
//
#include <hip/hip_runtime.h>

#define N_  50000
#define E_  800000
#define NBD 391        // dst bins of 128 nodes: (50000+127)/128
#define NBS 98         // src bins of 512 nodes: (50000+511)/512
#define CAPD 3072      // records per dst-bin list (mean 2048, +22 sigma)
#define CAPS 12032     // records per src-bin list (mean 8192, +42 sigma)
#define TPB_A 1024     // kbinA threads/block
#define EPB_A 4096     // kbinA edges/block (4 per thread)

typedef unsigned short u16;
typedef short short8 __attribute__((ext_vector_type(8)));
typedef float f32x4  __attribute__((ext_vector_type(4)));

// workspace byte offsets (256-aligned; ws_size = 256 MiB per harness poison, no overlays needed)
#define B_DINV   0u          // N f32: dinv (written wholesale by kdeg)
#define B_S      200192u     // N*64 bf16: S = -dinv * G2 (dense, stride 64)
#define B_XS     6600448u    // N*64 bf16: xs = dinv*x (plain x where dinv==0)
#define B_TX1S   13000704u   // N*64 bf16: Tx1s = dinv^2 * (-G1)
#define B_LISTS  19400960u   // NBS x CAPS x 8B src-bin lists {src, w_f32}
#define B_LISTD  28834048u   // NBD x CAPD x 8B dst-bin lists {src|ew_bf16<<16, dst}
#define B_GCNTD  38443264u   // NBD i32 global dst-bin counters
#define B_GCNTS  38445056u   // NBS i32 global src-bin counters
#define B_BT     38445568u   // 128 x 200 bf16 combined dense weights (transposed)
#define B_BIASM  38496768u   // 128 f32
#define B_BTL    38497280u   // 64 x 72 bf16 W_lin^T
#define B_BIASL  38506496u   // 64 f32

__device__ __forceinline__ float bf2f(u16 u) {
  union { unsigned int i; float f; } v; v.i = ((unsigned int)u) << 16; return v.f;
}
__device__ __forceinline__ u16 f2bf(float f) {
  union { float f; unsigned int i; } v; v.f = f;
  unsigned int r = v.i + 0x7fffu + ((v.i >> 16) & 1u);  // RNE, finite only
  return (u16)(r >> 16);
}
__device__ __forceinline__ short8 scale8(short8 v, float sc) {
  short8 r;
  #pragma unroll
  for (int i = 0; i < 8; ++i) r[i] = (short)f2bf(bf2f((u16)v[i]) * sc);
  return r;
}

// Combined dense weights: Bt[n][k], n in [0,128) output col (n<64 z-branch, else h-branch),
// k in [0,192): k<64 -> W[0]-W[2] (Tx2=2S-x fold), k<128 -> W[1], else 2*W[2].
__global__ void kprep(const float* Wxz, const float* Wxh, const float* bxz, const float* bhz,
                      const float* bxh, const float* bhh, const float* Wlin, const float* blin,
                      u16* Bt, float* biasM, u16* BtL, float* biasL) {
  int n = blockIdx.x, tid = threadIdx.x, c = n & 63;
  const float* W = (n < 64) ? Wxz : Wxh;
  if (tid < 192) {
    int k = tid; float v;
    if (k < 64)       v = W[k*64 + c] - W[2*4096 + k*64 + c];
    else if (k < 128) v = W[4096 + (k-64)*64 + c];
    else              v = 2.0f * W[2*4096 + (k-128)*64 + c];
    Bt[n*200 + k] = f2bf(v);
  } else if (tid < 200) Bt[n*200 + tid] = 0;
  if (tid == 0) biasM[n] = (n < 64) ? (bxz[c] + bhz[c]) : (bxh[c] + bhh[c]);
  if (n < 64) {
    if (tid < 64)      BtL[n*72 + tid] = f2bf(Wlin[tid*64 + n]);
    else if (tid < 72) BtL[n*72 + tid] = 0;
    if (tid == 0)      biasL[n] = blin[n];
  }
}

// Phase A: coalesced edge read; dual binning (dst 128-wide for fused gather, src 512-wide
// for deg) via LDS histograms + scan + 32KB LDS staging; cooperative wave-coalesced flush.
__global__ __launch_bounds__(1024) void kbinA(const int* __restrict__ ei,
                                              const float* __restrict__ ew,
                                              int* gcntD, int* gcntS,
                                              uint2* listD, uint2* listS) {
  __shared__ int histD[NBD], gbD[NBD], scan[512];
  __shared__ int histS[NBS], pfxS[NBS], gbS[NBS];
  __shared__ __align__(16) uint2 stg[EPB_A];
  int tid = threadIdx.x;
  if (tid < NBD) histD[tid] = 0;
  if (tid < NBS) histS[tid] = 0;
  __syncthreads();
  int base = blockIdx.x * EPB_A + tid;
  unsigned recw[4]; int dd[4], ss[4], slotD[4], slotS[4]; float wv[4];
  #pragma unroll
  for (int j = 0; j < 4; ++j) {
    int e = base + j * TPB_A;
    if (e < E_) {
      int s = ei[e], d = ei[E_ + e];
      float w = ew[e];
      recw[j] = (unsigned)s | ((unsigned)f2bf(w) << 16);
      wv[j] = w; dd[j] = d; ss[j] = s;
      slotD[j] = atomicAdd(&histD[d >> 7], 1);   // LDS return-atomic
      slotS[j] = atomicAdd(&histS[s >> 9], 1);
    } else { dd[j] = -1; ss[j] = -1; }
  }
  __syncthreads();
  // Hillis-Steele inclusive scan of histD (padded to 512) -> exclusive in scan[]
  if (tid < 512) scan[tid] = (tid < NBD) ? histD[tid] : 0;
  __syncthreads();
  for (int off = 1; off < 512; off <<= 1) {
    int v = 0;
    if (tid < 512 && tid >= off) v = scan[tid - off];
    __syncthreads();
    if (tid < 512) scan[tid] += v;
    __syncthreads();
  }
  int ex = 0;
  if (tid < 512) ex = scan[tid] - ((tid < NBD) ? histD[tid] : 0);
  __syncthreads();
  if (tid < 512) scan[tid] = ex;
  if (tid < NBD) gbD[tid] = histD[tid] ? atomicAdd(gcntD + tid, histD[tid]) : 0;
  if (tid < NBS) {   // serial exclusive scan over 98 bins + reserve
    int s = 0;
    for (int j = 0; j < tid; ++j) s += histS[j];
    pfxS[tid] = s;
    gbS[tid] = histS[tid] ? atomicAdd(gcntS + tid, histS[tid]) : 0;
  }
  __syncthreads();
  // ---- stage & flush dst-list (wave-coalesced)
  #pragma unroll
  for (int j = 0; j < 4; ++j)
    if (dd[j] >= 0) {
      int b = dd[j] >> 7;
      stg[scan[b] + slotD[j]] = (uint2){recw[j], (unsigned)dd[j]};
    }
  __syncthreads();
  int tot = scan[NBD - 1] + histD[NBD - 1];
  for (int i = tid; i < tot; i += TPB_A) {
    int lo = 0, hi = NBD - 1;                    // upper_bound on exclusive prefix
    while (lo < hi) { int mid = (lo + hi + 1) >> 1; if (scan[mid] <= i) lo = mid; else hi = mid - 1; }
    int pos = gbD[lo] + (i - scan[lo]);
    if (pos < CAPD) listD[(size_t)lo * CAPD + pos] = stg[i];
  }
  __syncthreads();
  // ---- stage & flush src-list {src, w_f32} (exact f32 weight for deg)
  #pragma unroll
  for (int j = 0; j < 4; ++j)
    if (ss[j] >= 0) {
      union { float f; unsigned u; } cv; cv.f = wv[j];
      stg[pfxS[ss[j] >> 9] + slotS[j]] = (uint2){(unsigned)ss[j], cv.u};
    }
  __syncthreads();
  int totS = pfxS[NBS - 1] + histS[NBS - 1];
  for (int i = tid; i < totS; i += TPB_A) {
    int lo = 0, hi = NBS - 1;
    while (lo < hi) { int mid = (lo + hi + 1) >> 1; if (pfxS[mid] <= i) lo = mid; else hi = mid - 1; }
    int pos = gbS[lo] + (i - pfxS[lo]);
    if (pos < CAPS) listS[(size_t)lo * CAPS + pos] = stg[i];
  }
}

// deg + dinv + xs fused: LDS f32 accumulators over the 512-node src bin, then dinv and
// xs = dinv*x (bf16, plain x where dinv==0) written coalesced from the same block.
__global__ __launch_bounds__(1024) void kdeg(const int* __restrict__ gcntS,
                                             const uint2* __restrict__ listS,
                                             const float* __restrict__ x,
                                             float* __restrict__ dinv, u16* __restrict__ xs) {
  __shared__ float acc[512];
  int b = blockIdx.x, tid = threadIdx.x;
  if (tid < 512) acc[tid] = 0.f;
  __syncthreads();
  int m = gcntS[b]; if (m > CAPS) m = CAPS;
  const uint2* lp = listS + (size_t)b * CAPS;
  for (int i = tid; i < m; i += 1024) {
    uint2 r = lp[i];
    union { unsigned u; float f; } cv; cv.u = r.y;
    atomicAdd(&acc[r.x & 511], cv.f);
  }
  __syncthreads();
  float dv = 0.f, sc = 1.f;
  if (tid < 512) {
    float d = acc[tid];
    dv = (d > 0.f) ? rsqrtf(d) : 0.f;
    sc = (d > 0.f) ? dv : 1.0f;
  }
  __syncthreads();
  if (tid < 512) {
    acc[tid] = sc;
    int n = b * 512 + tid;
    if (n < N_) dinv[n] = dv;
  }
  __syncthreads();
  int nbase = b * 512;
  for (int i = tid; i < 8192; i += 1024) {   // 512 nodes x 16 float4
    int nl = i >> 4, q = i & 15;
    int n = nbase + nl;
    if (n >= N_) break;                      // nl monotone per thread
    float4 xv = ((const float4*)x)[(size_t)n * 16 + q];
    float s = acc[nl];
    ushort4 ov = { f2bf(xv.x * s), f2bf(xv.y * s), f2bf(xv.z * s), f2bf(xv.w * s) };
    ((ushort4*)xs)[(size_t)n * 16 + q] = ov;
  }
}

// Fused gather: one block per 128-node dst bin; LDS f32 tile acc[128][64]; per record all
// 64 lanes read one source row (128B coalesced) and ds_add_f32 into the dst row (2 lanes/
// bank = conflict-free). mode=1: out = -dinv^2 * sum (Tx1s); mode=0: out = -dinv * sum (S).
__global__ __launch_bounds__(1024) void kgat(const u16* __restrict__ srcp,
                                             const int* __restrict__ gcntD,
                                             const uint2* __restrict__ listD,
                                             const float* __restrict__ dinv,
                                             u16* __restrict__ dstp, int mode) {
  __shared__ float accf[8192];   // [128][64]
  __shared__ float sdv[128];
  int b = blockIdx.x, tid = threadIdx.x;
  int lane = tid & 63, wave = tid >> 6;      // 16 waves
  for (int i = tid; i < 8192; i += 1024) accf[i] = 0.f;
  if (tid < 128) { int n = b * 128 + tid; sdv[tid] = (n < N_) ? dinv[n] : 0.f; }
  __syncthreads();
  int m = gcntD[b]; if (m > CAPD) m = CAPD;
  const uint2* lp = listD + (size_t)b * CAPD;
  for (int i0 = wave * 4; i0 < m; i0 += 64) {
    int k1 = m - i0; if (k1 > 4) k1 = 4;
    uint2 r[4];
    #pragma unroll
    for (int k = 0; k < 4; ++k) if (k < k1) r[k] = lp[i0 + k];
    float w[4], v[4]; int dl[4];
    #pragma unroll
    for (int k = 0; k < 4; ++k) if (k < k1) {
      w[k] = bf2f((u16)(r[k].x >> 16));
      dl[k] = (int)(r[k].y & 127u);
      v[k] = bf2f(srcp[(size_t)(r[k].x & 0xffffu) * 64 + lane]);
    }
    #pragma unroll
    for (int k = 0; k < 4; ++k) if (k < k1)
      atomicAdd(&accf[(dl[k] << 6) + lane], w[k] * v[k]);
  }
  __syncthreads();
  for (int i = tid; i < 4096; i += 1024) {   // 128 nodes x 32 u32 (2 bf16 each)
    int nl = i >> 5, fp = i & 31;
    int n = b * 128 + nl;
    if (n >= N_) break;
    float dv = sdv[nl];
    float sc = mode ? (-dv * dv) : (-dv);
    float v0 = accf[(nl << 6) + fp * 2]     * sc;
    float v1 = accf[(nl << 6) + fp * 2 + 1] * sc;
    unsigned ow = (unsigned)f2bf(v0) | ((unsigned)f2bf(v1) << 16);
    ((unsigned*)dstp)[(size_t)n * 32 + fp] = ow;
  }
}

// Pure dense: 128 rows/block. [128x192]@[192x128] -> gate -> [128x64]@[64x64] -> out.
// mfma_f32_16x16x32_bf16: A[m=lane&15][k=quad*8+j], B[k][n=lane&15], D col=lane&15,row=quad*4+reg
// x and Tx1 features reconstructed from scaled arrays via rc = 1/dinv (rc=1 for dinv==0,
// where xs holds plain x and Tx1s==0 — exact). S rows dense, stride 64.
__global__ __launch_bounds__(256) void kgemm(
    const u16* __restrict__ xs, const u16* __restrict__ Tx1s, const u16* __restrict__ Sb,
    const float* __restrict__ dinv,
    const u16* __restrict__ Bt, const float* __restrict__ biasM,
    const u16* __restrict__ BtL, const float* __restrict__ biasL,
    float* __restrict__ out) {
  __shared__ __align__(16) u16 sBt[25600];  // phase1: Bt 128x200 (51200B); phase2: H 128x72 @0 | BtL @9216
  int tid = threadIdx.x, wave = tid >> 6, lane = tid & 63;
  int m16 = lane & 15, quad = lane >> 4;
  int row_base = blockIdx.x * 128;

  for (int i = tid; i < 3200; i += 256)
    ((uint4*)sBt)[i] = ((const uint4*)Bt)[i];

  short8 a[2][6];
  #pragma unroll
  for (int h = 0; h < 2; ++h) {
    int r = row_base + (wave * 2 + h) * 16 + m16;
    if (r < N_) {
      float dv = dinv[r];
      float rc = (dv > 0.f) ? (1.0f / dv) : 1.0f;
      const u16* xr = xs   + (size_t)r * 64;
      const u16* tr = Tx1s + (size_t)r * 64;
      const u16* sr = Sb   + (size_t)r * 64;
      a[h][0] = scale8(*(const short8*)(xr + quad * 8), rc);
      a[h][1] = scale8(*(const short8*)(xr + 32 + quad * 8), rc);
      a[h][2] = scale8(*(const short8*)(tr + quad * 8), rc);
      a[h][3] = scale8(*(const short8*)(tr + 32 + quad * 8), rc);
      a[h][4] = *(const short8*)(sr + quad * 8);
      a[h][5] = *(const short8*)(sr + 32 + quad * 8);
    } else {
      short8 z = {0,0,0,0,0,0,0,0};
      #pragma unroll
      for (int s = 0; s < 6; ++s) a[h][s] = z;
    }
  }
  __syncthreads();

  f32x4 acc[2][8];
  #pragma unroll
  for (int h = 0; h < 2; ++h)
    #pragma unroll
    for (int t = 0; t < 8; ++t) acc[h][t] = (f32x4){0.f, 0.f, 0.f, 0.f};
  #pragma unroll
  for (int t = 0; t < 8; ++t) {
    const u16* brow = sBt + (t * 16 + m16) * 200;
    #pragma unroll
    for (int s = 0; s < 6; ++s) {
      short8 b = *(const short8*)(brow + s * 32 + quad * 8);
      acc[0][t] = __builtin_amdgcn_mfma_f32_16x16x32_bf16(a[0][s], b, acc[0][t], 0, 0, 0);
      acc[1][t] = __builtin_amdgcn_mfma_f32_16x16x32_bf16(a[1][s], b, acc[1][t], 0, 0, 0);
    }
  }
  __syncthreads();

  // gate: H = relu( tanh(hpre) * (1 - sigmoid(zpre)) ) -> bf16 rows @ sBt, stride 72
  #pragma unroll
  for (int h = 0; h < 2; ++h) {
    #pragma unroll
    for (int t = 0; t < 4; ++t) {
      int c = t * 16 + m16;
      float bz = biasM[c], bh = biasM[64 + c];
      #pragma unroll
      for (int rr = 0; rr < 4; ++rr) {
        float z  = acc[h][t][rr] + bz;
        float hp = acc[h][t + 4][rr] + bh;
        float th = 1.0f - 2.0f / (__expf(2.0f * hp) + 1.0f);
        float hv = th / (1.0f + __expf(z));
        hv = fmaxf(hv, 0.0f);
        sBt[((wave * 2 + h) * 16 + quad * 4 + rr) * 72 + c] = f2bf(hv);
      }
    }
  }
  for (int i = tid; i < 576; i += 256)
    ((uint4*)(sBt + 9216))[i] = ((const uint4*)BtL)[i];
  __syncthreads();

  short8 a2[2][2];
  #pragma unroll
  for (int h = 0; h < 2; ++h) {
    const u16* hrow = sBt + ((wave * 2 + h) * 16 + m16) * 72;
    a2[h][0] = *(const short8*)(hrow + quad * 8);
    a2[h][1] = *(const short8*)(hrow + 32 + quad * 8);
  }
  f32x4 acc2[2][4];
  #pragma unroll
  for (int h = 0; h < 2; ++h)
    #pragma unroll
    for (int t = 0; t < 4; ++t) acc2[h][t] = (f32x4){0.f, 0.f, 0.f, 0.f};
  #pragma unroll
  for (int t = 0; t < 4; ++t) {
    const u16* brow = sBt + 9216 + (t * 16 + m16) * 72;
    short8 b0 = *(const short8*)(brow + quad * 8);
    short8 b1 = *(const short8*)(brow + 32 + quad * 8);
    #pragma unroll
    for (int h = 0; h < 2; ++h) {
      acc2[h][t] = __builtin_amdgcn_mfma_f32_16x16x32_bf16(a2[h][0], b0, acc2[h][t], 0, 0, 0);
      acc2[h][t] = __builtin_amdgcn_mfma_f32_16x16x32_bf16(a2[h][1], b1, acc2[h][t], 0, 0, 0);
    }
  }
  #pragma unroll
  for (int h = 0; h < 2; ++h) {
    #pragma unroll
    for (int t = 0; t < 4; ++t) {
      int c = t * 16 + m16;
      float bl = biasL[c];
      #pragma unroll
      for (int rr = 0; rr < 4; ++rr) {
        int nr = row_base + (wave * 2 + h) * 16 + quad * 4 + rr;
        if (nr < N_) out[(size_t)nr * 64 + c] = acc2[h][t][rr] + bl;
      }
    }
  }
}

extern "C" void kernel_launch(void* const* d_in, const int* in_sizes, int n_in,
                              void* d_out, int out_size, void* d_ws, size_t ws_size,
                              hipStream_t stream) {
  const float* x    = (const float*)d_in[0];
  const int*   ei   = (const int*)d_in[1];
  const float* ew   = (const float*)d_in[2];
  const float* Wxz  = (const float*)d_in[3];
  const float* bxz  = (const float*)d_in[4];
  const float* bhz  = (const float*)d_in[6];
  const float* Wxh  = (const float*)d_in[11];
  const float* bxh  = (const float*)d_in[12];
  const float* bhh  = (const float*)d_in[14];
  const float* Wlin = (const float*)d_in[15];
  const float* blin = (const float*)d_in[16];
  float* out = (float*)d_out;

  char* ws = (char*)d_ws;
  float*    dinv  = (float*)   (ws + B_DINV);
  u16*      Sb    = (u16*)     (ws + B_S);
  u16*      xsb   = (u16*)     (ws + B_XS);
  u16*      Tx1s  = (u16*)     (ws + B_TX1S);
  uint2*    listS = (uint2*)   (ws + B_LISTS);
  uint2*    listD = (uint2*)   (ws + B_LISTD);
  int*      gcntD = (int*)     (ws + B_GCNTD);
  int*      gcntS = (int*)     (ws + B_GCNTS);
  u16*      Bt    = (u16*)     (ws + B_BT);
  float*    biasM = (float*)   (ws + B_BIASM);
  u16*      BtL   = (u16*)     (ws + B_BTL);
  float*    biasL = (float*)   (ws + B_BIASL);

  hipMemsetAsync(ws + B_GCNTD, 0, 2304, stream);   // gcntD + gcntS
  kprep <<<128, 256, 0, stream>>>(Wxz, Wxh, bxz, bhz, bxh, bhh, Wlin, blin, Bt, biasM, BtL, biasL);
  kbinA <<<(E_ + EPB_A - 1) / EPB_A, TPB_A, 0, stream>>>(ei, ew, gcntD, gcntS, listD, listS);
  kdeg  <<<NBS, 1024, 0, stream>>>(gcntS, listS, x, dinv, xsb);
  kgat  <<<NBD, 1024, 0, stream>>>(xsb,  gcntD, listD, dinv, Tx1s, 1);  // Tx1s = -dinv^2 * G1
  kgat  <<<NBD, 1024, 0, stream>>>(Tx1s, gcntD, listD, dinv, Sb,   0);  // S    = -dinv   * G2
  kgemm <<<(N_ + 127) / 128, 256, 0, stream>>>(xsb, Tx1s, Sb, dinv, Bt, biasM, BtL, biasL, out);
}

// Round 5
// 207.865 us; speedup vs baseline: 4.0859x; 4.0859x over previous
//
#include <hip/hip_runtime.h>

#define N_  50000
#define E_  800000
#define BKT 48         // bucket capacity per node (Poisson(16): P(deg>=48)~1e-9)
#define NBIN 98        // bins of 512 nodes: (50000+511)/512
#define BIN_SH 9
#define CAPD 12032     // records per dst-bin list (mean 8192, +42 sigma)
#define CAPS 12032     // records per src-bin list
#define TPB_A 1024     // kbinA threads/block
#define EPB_A 4096     // kbinA edges/block (4 per thread)

typedef unsigned short u16;
typedef short short8 __attribute__((ext_vector_type(8)));
typedef float f32x4  __attribute__((ext_vector_type(4)));

// workspace byte offsets (256-aligned). ws_size = 256 MiB (per harness poison) -> no overlays.
#define B_DINV   0u          // N f32: dinv (written wholesale by kdeg)
#define B_CNT    200192u     // N i32: per-dst edge count (written wholesale by kfill)
#define B_BKT    400384u     // N x BKT u32 records {ew_bf16<<16 | src}, stride 192B
#define B_XS     10000384u   // N*64 bf16: xs = dinv*x (plain x where dinv==0)
#define B_TX1S   16400384u   // N*64 bf16: Tx1s = dinv^2 * (-G1)
#define B_S      22800384u   // N*64 bf16: S = -dinv * G2 (dense, stride 64)
#define B_LISTD  29200384u   // NBIN x CAPD x 8B dst-bin lists {src|ew_bf16<<16, dst}
#define B_LISTS  38633472u   // NBIN x CAPS x 8B src-bin lists {src, w_f32}
#define B_GCNTD  48066560u   // NBIN i32 global dst-bin counters
#define B_GCNTS  48067072u   // NBIN i32 global src-bin counters
#define B_BT     48067584u   // 128 x 200 bf16 combined dense weights (transposed)
#define B_BIASM  48118784u   // 128 f32
#define B_BTL    48119296u   // 64 x 72 bf16 W_lin^T
#define B_BIASL  48128512u   // 64 f32

__device__ __forceinline__ float bf2f(u16 u) {
  union { unsigned int i; float f; } v; v.i = ((unsigned int)u) << 16; return v.f;
}
__device__ __forceinline__ u16 f2bf(float f) {
  union { float f; unsigned int i; } v; v.f = f;
  unsigned int r = v.i + 0x7fffu + ((v.i >> 16) & 1u);  // RNE, finite only
  return (u16)(r >> 16);
}
__device__ __forceinline__ short8 scale8(short8 v, float sc) {
  short8 r;
  #pragma unroll
  for (int i = 0; i < 8; ++i) r[i] = (short)f2bf(bf2f((u16)v[i]) * sc);
  return r;
}

// Combined dense weights: Bt[n][k], n in [0,128) output col (n<64 z-branch, else h-branch),
// k in [0,192): k<64 -> W[0]-W[2] (Tx2=2S-x fold), k<128 -> W[1], else 2*W[2].
__global__ void kprep(const float* Wxz, const float* Wxh, const float* bxz, const float* bhz,
                      const float* bxh, const float* bhh, const float* Wlin, const float* blin,
                      u16* Bt, float* biasM, u16* BtL, float* biasL) {
  int n = blockIdx.x, tid = threadIdx.x, c = n & 63;
  const float* W = (n < 64) ? Wxz : Wxh;
  if (tid < 192) {
    int k = tid; float v;
    if (k < 64)       v = W[k*64 + c] - W[2*4096 + k*64 + c];
    else if (k < 128) v = W[4096 + (k-64)*64 + c];
    else              v = 2.0f * W[2*4096 + (k-128)*64 + c];
    Bt[n*200 + k] = f2bf(v);
  } else if (tid < 200) Bt[n*200 + tid] = 0;
  if (tid == 0) biasM[n] = (n < 64) ? (bxz[c] + bhz[c]) : (bxh[c] + bhh[c]);
  if (n < 64) {
    if (tid < 64)      BtL[n*72 + tid] = f2bf(Wlin[tid*64 + n]);
    else if (tid < 72) BtL[n*72 + tid] = 0;
    if (tid == 0)      biasL[n] = blin[n];
  }
}

// Phase A: coalesced edge read; dual binning (dst-bin for bucket CSR, src-bin for deg) via
// LDS histograms + prefix scan + 32KB LDS staging; cooperative flush so consecutive lanes
// write consecutive addresses (wave-coalesced). No global atomics except one reserve per
// (block,bin). [round-3 proven version]
__global__ __launch_bounds__(1024) void kbinA(const int* __restrict__ ei,
                                              const float* __restrict__ ew,
                                              int* gcntD, int* gcntS,
                                              uint2* listD, uint2* listS) {
  __shared__ int histD[NBIN], pfxD[NBIN], gbD[NBIN];
  __shared__ int histS[NBIN], pfxS[NBIN], gbS[NBIN];
  __shared__ __align__(16) uint2 stg[EPB_A];
  int tid = threadIdx.x;
  if (tid < NBIN) { histD[tid] = 0; histS[tid] = 0; }
  __syncthreads();
  int base = blockIdx.x * EPB_A + tid;
  unsigned recw[4]; int dd[4], ss[4], slotD[4], slotS[4]; float wv[4];
  #pragma unroll
  for (int j = 0; j < 4; ++j) {
    int e = base + j * TPB_A;
    if (e < E_) {
      int s = ei[e], d = ei[E_ + e];
      float w = ew[e];
      recw[j] = (unsigned)s | ((unsigned)f2bf(w) << 16);
      wv[j] = w; dd[j] = d; ss[j] = s;
      slotD[j] = atomicAdd(&histD[d >> BIN_SH], 1);  // LDS return-atomic
      slotS[j] = atomicAdd(&histS[s >> BIN_SH], 1);
    } else { dd[j] = -1; ss[j] = -1; }
  }
  __syncthreads();
  if (tid < NBIN) {  // exclusive scan (all-broadcast LDS reads) + global reserve
    int sD = 0, sS = 0;
    for (int j = 0; j < tid; ++j) { sD += histD[j]; sS += histS[j]; }
    pfxD[tid] = sD; pfxS[tid] = sS;
    gbD[tid] = histD[tid] ? atomicAdd(gcntD + tid, histD[tid]) : 0;
    gbS[tid] = histS[tid] ? atomicAdd(gcntS + tid, histS[tid]) : 0;
  }
  __syncthreads();
  // ---- stage & flush dst-list
  #pragma unroll
  for (int j = 0; j < 4; ++j)
    if (dd[j] >= 0) stg[pfxD[dd[j] >> BIN_SH] + slotD[j]] = (uint2){recw[j], (unsigned)dd[j]};
  __syncthreads();
  int tot = pfxD[NBIN - 1] + histD[NBIN - 1];
  for (int i = tid; i < tot; i += TPB_A) {
    int lo = 0, hi = NBIN - 1;                    // upper_bound on pfxD
    while (lo < hi) { int mid = (lo + hi + 1) >> 1; if (pfxD[mid] <= i) lo = mid; else hi = mid - 1; }
    int pos = gbD[lo] + (i - pfxD[lo]);
    if (pos < CAPD) listD[(size_t)lo * CAPD + pos] = stg[i];
  }
  __syncthreads();
  // ---- stage & flush src-list {src, w_f32} (exact f32 weight for deg)
  #pragma unroll
  for (int j = 0; j < 4; ++j)
    if (ss[j] >= 0) {
      union { float f; unsigned u; } cv; cv.f = wv[j];
      stg[pfxS[ss[j] >> BIN_SH] + slotS[j]] = (uint2){(unsigned)ss[j], cv.u};
    }
  __syncthreads();
  int totS = pfxS[NBIN - 1] + histS[NBIN - 1];
  for (int i = tid; i < totS; i += TPB_A) {
    int lo = 0, hi = NBIN - 1;
    while (lo < hi) { int mid = (lo + hi + 1) >> 1; if (pfxS[mid] <= i) lo = mid; else hi = mid - 1; }
    int pos = gbS[lo] + (i - pfxS[lo]);
    if (pos < CAPS) listS[(size_t)lo * CAPS + pos] = stg[i];
  }
}

// deg + dinv + xs fused: LDS f32 accumulators over the 512-node src bin, then dinv and
// xs = dinv*x (bf16, plain x where dinv==0 -- exact: such nodes are never gather-read)
// written coalesced from the same block. [validated in round 4]
__global__ __launch_bounds__(1024) void kdeg(const int* __restrict__ gcntS,
                                             const uint2* __restrict__ listS,
                                             const float* __restrict__ x,
                                             float* __restrict__ dinv, u16* __restrict__ xs) {
  __shared__ float acc[512];
  int b = blockIdx.x, tid = threadIdx.x;
  if (tid < 512) acc[tid] = 0.f;
  __syncthreads();
  int m = gcntS[b]; if (m > CAPS) m = CAPS;
  const uint2* lp = listS + (size_t)b * CAPS;
  for (int i = tid; i < m; i += 1024) {
    uint2 r = lp[i];
    union { unsigned u; float f; } cv; cv.u = r.y;
    atomicAdd(&acc[r.x & 511], cv.f);
  }
  __syncthreads();
  float dv = 0.f, sc = 1.f;
  if (tid < 512) {
    float d = acc[tid];
    dv = (d > 0.f) ? rsqrtf(d) : 0.f;
    sc = (d > 0.f) ? dv : 1.0f;
  }
  __syncthreads();
  if (tid < 512) {
    acc[tid] = sc;
    int n = b * 512 + tid;
    if (n < N_) dinv[n] = dv;
  }
  __syncthreads();
  int nbase = b * 512;
  for (int i = tid; i < 8192; i += 1024) {   // 512 nodes x 16 float4
    int nl = i >> 4, q = i & 15;
    int n = nbase + nl;
    if (n >= N_) break;                      // nl monotone per thread
    float4 xv = ((const float4*)x)[(size_t)n * 16 + q];
    float s = acc[nl];
    ushort4 ov = { f2bf(xv.x * s), f2bf(xv.y * s), f2bf(xv.z * s), f2bf(xv.w * s) };
    ((ushort4*)xs)[(size_t)n * 16 + q] = ov;
  }
}

// Phase B: one workgroup per 512-node bin. Slot assignment in LDS (512 counters); bucket
// stores land in the bin's 96KB L2-hot region; cnt written out coalesced.
__global__ __launch_bounds__(1024) void kfill(const int* __restrict__ gcntD,
                                              const uint2* __restrict__ listD,
                                              unsigned* bkt, int* cnt) {
  __shared__ int lcnt[512];
  int b = blockIdx.x, tid = threadIdx.x;
  if (tid < 512) lcnt[tid] = 0;
  __syncthreads();
  int m = gcntD[b]; if (m > CAPD) m = CAPD;
  const uint2* lp = listD + (size_t)b * CAPD;
  for (int i = tid; i < m; i += 1024) {
    uint2 r = lp[i];
    int node = (int)r.y;
    int s = atomicAdd(&lcnt[node & 511], 1);
    if (s < BKT) bkt[(size_t)node * BKT + s] = r.x;
  }
  __syncthreads();
  int n = b * 512 + tid;
  if (tid < 512 && n < N_) cnt[n] = lcnt[tid];
}

// out[n] = scale(n) * sum_e ew_e * src[s_e], 2 nodes/wave (32 lanes, lane = u32 feature pair).
// mode=1: scale = -dinv[n]^2 (writes scaled Tx1s); mode=0: scale = -dinv[n] (writes S).
// 6250 blocks -> 25k independent half-waves: latency hidden by TLP (round-4 lesson: the
// per-bin LDS-accumulate variant serializes and is 7x slower).
__global__ __launch_bounds__(256) void kgather(
    const u16* __restrict__ srcp, const int* __restrict__ cnt, const float* __restrict__ dinv,
    const unsigned* bkt, u16* dstp, int mode) {
  int n = blockIdx.x * 8 + (threadIdx.x >> 5);
  if (n >= N_) return;
  int li = threadIdx.x & 31;
  int c = cnt[n]; c = (c > BKT) ? BKT : c;
  const unsigned* recs = bkt + (size_t)n * BKT;
  float a0 = 0.f, a1 = 0.f, b0 = 0.f, b1 = 0.f, c0 = 0.f, c1 = 0.f, d0 = 0.f, d1 = 0.f;
  int j = 0;
  for (; j + 3 < c; j += 4) {
    unsigned r0 = recs[j], r1 = recs[j + 1], r2 = recs[j + 2], r3 = recs[j + 3];
    float w0 = bf2f((u16)(r0 >> 16)), w1 = bf2f((u16)(r1 >> 16));
    float w2 = bf2f((u16)(r2 >> 16)), w3 = bf2f((u16)(r3 >> 16));
    unsigned p0 = *(const unsigned*)(srcp + (size_t)(r0 & 0xffffu) * 64 + li * 2);
    unsigned p1 = *(const unsigned*)(srcp + (size_t)(r1 & 0xffffu) * 64 + li * 2);
    unsigned p2 = *(const unsigned*)(srcp + (size_t)(r2 & 0xffffu) * 64 + li * 2);
    unsigned p3 = *(const unsigned*)(srcp + (size_t)(r3 & 0xffffu) * 64 + li * 2);
    a0 += w0 * bf2f((u16)p0); a1 += w0 * bf2f((u16)(p0 >> 16));
    b0 += w1 * bf2f((u16)p1); b1 += w1 * bf2f((u16)(p1 >> 16));
    c0 += w2 * bf2f((u16)p2); c1 += w2 * bf2f((u16)(p2 >> 16));
    d0 += w3 * bf2f((u16)p3); d1 += w3 * bf2f((u16)(p3 >> 16));
  }
  for (; j < c; ++j) {
    unsigned r0 = recs[j];
    float w0 = bf2f((u16)(r0 >> 16));
    unsigned p0 = *(const unsigned*)(srcp + (size_t)(r0 & 0xffffu) * 64 + li * 2);
    a0 += w0 * bf2f((u16)p0); a1 += w0 * bf2f((u16)(p0 >> 16));
  }
  a0 += b0; c0 += d0; a0 += c0;
  a1 += b1; c1 += d1; a1 += c1;
  float dv = dinv[n];
  float sc = mode ? (-dv * dv) : (-dv);
  a0 *= sc; a1 *= sc;
  unsigned outw = (unsigned)f2bf(a0) | ((unsigned)f2bf(a1) << 16);
  *(unsigned*)(dstp + (size_t)n * 64 + li * 2) = outw;
}

// Pure dense: 128 rows/block. [128x192]@[192x128] -> gate -> [128x64]@[64x64] -> out.
// mfma_f32_16x16x32_bf16: A[m=lane&15][k=quad*8+j], B[k][n=lane&15], D col=lane&15,row=quad*4+reg
// x and Tx1 features reconstructed from scaled arrays via rc = 1/dinv (rc=1 for dinv==0,
// where xs holds plain x and Tx1s==0 -- exact). S rows dense, stride 64.
__global__ __launch_bounds__(256) void kgemm(
    const u16* __restrict__ xs, const u16* __restrict__ Tx1s, const u16* __restrict__ Sb,
    const float* __restrict__ dinv,
    const u16* __restrict__ Bt, const float* __restrict__ biasM,
    const u16* __restrict__ BtL, const float* __restrict__ biasL,
    float* __restrict__ out) {
  __shared__ __align__(16) u16 sBt[25600];  // phase1: Bt 128x200 (51200B); phase2: H 128x72 @0 | BtL @9216
  int tid = threadIdx.x, wave = tid >> 6, lane = tid & 63;
  int m16 = lane & 15, quad = lane >> 4;
  int row_base = blockIdx.x * 128;

  for (int i = tid; i < 3200; i += 256)
    ((uint4*)sBt)[i] = ((const uint4*)Bt)[i];

  short8 a[2][6];
  #pragma unroll
  for (int h = 0; h < 2; ++h) {
    int r = row_base + (wave * 2 + h) * 16 + m16;
    if (r < N_) {
      float dv = dinv[r];
      float rc = (dv > 0.f) ? (1.0f / dv) : 1.0f;
      const u16* xr = xs   + (size_t)r * 64;
      const u16* tr = Tx1s + (size_t)r * 64;
      const u16* sr = Sb   + (size_t)r * 64;
      a[h][0] = scale8(*(const short8*)(xr + quad * 8), rc);
      a[h][1] = scale8(*(const short8*)(xr + 32 + quad * 8), rc);
      a[h][2] = scale8(*(const short8*)(tr + quad * 8), rc);
      a[h][3] = scale8(*(const short8*)(tr + 32 + quad * 8), rc);
      a[h][4] = *(const short8*)(sr + quad * 8);
      a[h][5] = *(const short8*)(sr + 32 + quad * 8);
    } else {
      short8 z = {0,0,0,0,0,0,0,0};
      #pragma unroll
      for (int s = 0; s < 6; ++s) a[h][s] = z;
    }
  }
  __syncthreads();

  f32x4 acc[2][8];
  #pragma unroll
  for (int h = 0; h < 2; ++h)
    #pragma unroll
    for (int t = 0; t < 8; ++t) acc[h][t] = (f32x4){0.f, 0.f, 0.f, 0.f};
  #pragma unroll
  for (int t = 0; t < 8; ++t) {
    const u16* brow = sBt + (t * 16 + m16) * 200;
    #pragma unroll
    for (int s = 0; s < 6; ++s) {
      short8 b = *(const short8*)(brow + s * 32 + quad * 8);
      acc[0][t] = __builtin_amdgcn_mfma_f32_16x16x32_bf16(a[0][s], b, acc[0][t], 0, 0, 0);
      acc[1][t] = __builtin_amdgcn_mfma_f32_16x16x32_bf16(a[1][s], b, acc[1][t], 0, 0, 0);
    }
  }
  __syncthreads();

  // gate: H = relu( tanh(hpre) * (1 - sigmoid(zpre)) ) -> bf16 rows @ sBt, stride 72
  #pragma unroll
  for (int h = 0; h < 2; ++h) {
    #pragma unroll
    for (int t = 0; t < 4; ++t) {
      int c = t * 16 + m16;
      float bz = biasM[c], bh = biasM[64 + c];
      #pragma unroll
      for (int rr = 0; rr < 4; ++rr) {
        float z  = acc[h][t][rr] + bz;
        float hp = acc[h][t + 4][rr] + bh;
        float th = 1.0f - 2.0f / (__expf(2.0f * hp) + 1.0f);
        float hv = th / (1.0f + __expf(z));
        hv = fmaxf(hv, 0.0f);
        sBt[((wave * 2 + h) * 16 + quad * 4 + rr) * 72 + c] = f2bf(hv);
      }
    }
  }
  for (int i = tid; i < 576; i += 256)
    ((uint4*)(sBt + 9216))[i] = ((const uint4*)BtL)[i];
  __syncthreads();

  short8 a2[2][2];
  #pragma unroll
  for (int h = 0; h < 2; ++h) {
    const u16* hrow = sBt + ((wave * 2 + h) * 16 + m16) * 72;
    a2[h][0] = *(const short8*)(hrow + quad * 8);
    a2[h][1] = *(const short8*)(hrow + 32 + quad * 8);
  }
  f32x4 acc2[2][4];
  #pragma unroll
  for (int h = 0; h < 2; ++h)
    #pragma unroll
    for (int t = 0; t < 4; ++t) acc2[h][t] = (f32x4){0.f, 0.f, 0.f, 0.f};
  #pragma unroll
  for (int t = 0; t < 4; ++t) {
    const u16* brow = sBt + 9216 + (t * 16 + m16) * 72;
    short8 b0 = *(const short8*)(brow + quad * 8);
    short8 b1 = *(const short8*)(brow + 32 + quad * 8);
    #pragma unroll
    for (int h = 0; h < 2; ++h) {
      acc2[h][t] = __builtin_amdgcn_mfma_f32_16x16x32_bf16(a2[h][0], b0, acc2[h][t], 0, 0, 0);
      acc2[h][t] = __builtin_amdgcn_mfma_f32_16x16x32_bf16(a2[h][1], b1, acc2[h][t], 0, 0, 0);
    }
  }
  #pragma unroll
  for (int h = 0; h < 2; ++h) {
    #pragma unroll
    for (int t = 0; t < 4; ++t) {
      int c = t * 16 + m16;
      float bl = biasL[c];
      #pragma unroll
      for (int rr = 0; rr < 4; ++rr) {
        int nr = row_base + (wave * 2 + h) * 16 + quad * 4 + rr;
        if (nr < N_) out[(size_t)nr * 64 + c] = acc2[h][t][rr] + bl;
      }
    }
  }
}

extern "C" void kernel_launch(void* const* d_in, const int* in_sizes, int n_in,
                              void* d_out, int out_size, void* d_ws, size_t ws_size,
                              hipStream_t stream) {
  const float* x    = (const float*)d_in[0];
  const int*   ei   = (const int*)d_in[1];
  const float* ew   = (const float*)d_in[2];
  const float* Wxz  = (const float*)d_in[3];
  const float* bxz  = (const float*)d_in[4];
  const float* bhz  = (const float*)d_in[6];
  const float* Wxh  = (const float*)d_in[11];
  const float* bxh  = (const float*)d_in[12];
  const float* bhh  = (const float*)d_in[14];
  const float* Wlin = (const float*)d_in[15];
  const float* blin = (const float*)d_in[16];
  float* out = (float*)d_out;

  char* ws = (char*)d_ws;
  float*    dinv  = (float*)   (ws + B_DINV);
  int*      cnt   = (int*)     (ws + B_CNT);
  unsigned* bkt   = (unsigned*)(ws + B_BKT);
  u16*      xsb   = (u16*)     (ws + B_XS);
  u16*      Tx1s  = (u16*)     (ws + B_TX1S);
  u16*      Sb    = (u16*)     (ws + B_S);
  uint2*    listD = (uint2*)   (ws + B_LISTD);
  uint2*    listS = (uint2*)   (ws + B_LISTS);
  int*      gcntD = (int*)     (ws + B_GCNTD);
  int*      gcntS = (int*)     (ws + B_GCNTS);
  u16*      Bt    = (u16*)     (ws + B_BT);
  float*    biasM = (float*)   (ws + B_BIASM);
  u16*      BtL   = (u16*)     (ws + B_BTL);
  float*    biasL = (float*)   (ws + B_BIASL);

  hipMemsetAsync(ws + B_GCNTD, 0, 1024, stream);   // gcntD + gcntS (contiguous)
  kprep  <<<128, 256, 0, stream>>>(Wxz, Wxh, bxz, bhz, bxh, bhh, Wlin, blin, Bt, biasM, BtL, biasL);
  kbinA  <<<(E_ + EPB_A - 1) / EPB_A, TPB_A, 0, stream>>>(ei, ew, gcntD, gcntS, listD, listS);
  kdeg   <<<NBIN, 1024, 0, stream>>>(gcntS, listS, x, dinv, xsb);
  kfill  <<<NBIN, 1024, 0, stream>>>(gcntD, listD, bkt, cnt);
  kgather<<<(N_ + 7) / 8, 256, 0, stream>>>(xsb,  cnt, dinv, bkt, Tx1s, 1);  // Tx1s = -dinv^2 * G1
  kgather<<<(N_ + 7) / 8, 256, 0, stream>>>(Tx1s, cnt, dinv, bkt, Sb,   0);  // S    = -dinv   * G2
  kgemm  <<<(N_ + 127) / 128, 256, 0, stream>>>(xsb, Tx1s, Sb, dinv, Bt, biasM, BtL, biasL, out);
}

// Round 6
// 191.361 us; speedup vs baseline: 4.4383x; 1.0862x over previous
//
#include <hip/hip_runtime.h>

#define N_  50000
#define E_  800000
#define BKT 48         // bucket capacity per node (Poisson(16): P(deg>=48)~1e-9)
#define NBIN 98        // bins of 512 nodes: (50000+511)/512
#define BIN_SH 9
#define CAPD 12032     // records per dst-bin list (mean 8192, +42 sigma)
#define CAPS 12032     // records per src-bin list
#define TPB_A 1024     // kbinA threads/block
#define EPB_A 4096     // kbinA edges/block (4 per thread)
#define GAUX (2 * NBIN + 128)   // kaux grid: deg bins | fill bins | prep blocks

typedef unsigned short u16;
typedef short short8 __attribute__((ext_vector_type(8)));
typedef float f32x4  __attribute__((ext_vector_type(4)));

// workspace byte offsets (256-aligned). ws_size = 256 MiB (per harness poison) -> no overlays.
#define B_DINV   0u          // N f32: dinv (written wholesale by kaux/deg)
#define B_CNT    200192u     // N i32: per-dst edge count (written wholesale by kaux/fill)
#define B_BKT    400384u     // N x BKT u32 records {ew_bf16<<16 | src}, stride 192B
#define B_XS     10000384u   // N*64 bf16: xs = dinv*x (plain x where dinv==0)
#define B_TX1S   16400384u   // N*64 bf16: Tx1s = dinv^2 * (-G1)
#define B_S      22800384u   // N*64 bf16: S = -dinv * G2 (dense, stride 64)
#define B_LISTD  29200384u   // NBIN x CAPD x 8B dst-bin lists {src|ew_bf16<<16, dst}
#define B_LISTS  38633472u   // NBIN x CAPS x 8B src-bin lists {src, w_f32}
#define B_GCNTD  48066560u   // NBIN i32 global dst-bin counters
#define B_GCNTS  48067072u   // NBIN i32 global src-bin counters
#define B_BT     48067584u   // 128 x 200 bf16 combined dense weights (transposed)
#define B_BIASM  48118784u   // 128 f32
#define B_BTL    48119296u   // 64 x 72 bf16 W_lin^T
#define B_BIASL  48128512u   // 64 f32

__device__ __forceinline__ float bf2f(u16 u) {
  union { unsigned int i; float f; } v; v.i = ((unsigned int)u) << 16; return v.f;
}
__device__ __forceinline__ u16 f2bf(float f) {
  union { float f; unsigned int i; } v; v.f = f;
  unsigned int r = v.i + 0x7fffu + ((v.i >> 16) & 1u);  // RNE, finite only
  return (u16)(r >> 16);
}
__device__ __forceinline__ short8 scale8(short8 v, float sc) {
  short8 r;
  #pragma unroll
  for (int i = 0; i < 8; ++i) r[i] = (short)f2bf(bf2f((u16)v[i]) * sc);
  return r;
}

// Phase A: coalesced edge read; dual binning (dst-bin for bucket CSR, src-bin for deg) via
// LDS histograms + prefix scan + 32KB LDS staging; cooperative flush so consecutive lanes
// write consecutive addresses (wave-coalesced). Flush bin recovered directly from the record
// (dst>>9 / src>>9) -- no binary search. One global reserve atomic per (block,bin).
__global__ __launch_bounds__(1024) void kbinA(const int* __restrict__ ei,
                                              const float* __restrict__ ew,
                                              int* gcntD, int* gcntS,
                                              uint2* listD, uint2* listS) {
  __shared__ int histD[NBIN], pfxD[NBIN], gbD[NBIN];
  __shared__ int histS[NBIN], pfxS[NBIN], gbS[NBIN];
  __shared__ __align__(16) uint2 stg[EPB_A];
  int tid = threadIdx.x;
  if (tid < NBIN) { histD[tid] = 0; histS[tid] = 0; }
  __syncthreads();
  int base = blockIdx.x * EPB_A + tid;
  unsigned recw[4]; int dd[4], ss[4], slotD[4], slotS[4]; float wv[4];
  #pragma unroll
  for (int j = 0; j < 4; ++j) {
    int e = base + j * TPB_A;
    if (e < E_) {
      int s = ei[e], d = ei[E_ + e];
      float w = ew[e];
      recw[j] = (unsigned)s | ((unsigned)f2bf(w) << 16);
      wv[j] = w; dd[j] = d; ss[j] = s;
      slotD[j] = atomicAdd(&histD[d >> BIN_SH], 1);  // LDS return-atomic
      slotS[j] = atomicAdd(&histS[s >> BIN_SH], 1);
    } else { dd[j] = -1; ss[j] = -1; }
  }
  __syncthreads();
  if (tid < NBIN) {  // exclusive scan (all-broadcast LDS reads) + global reserve
    int sD = 0, sS = 0;
    for (int j = 0; j < tid; ++j) { sD += histD[j]; sS += histS[j]; }
    pfxD[tid] = sD; pfxS[tid] = sS;
    gbD[tid] = histD[tid] ? atomicAdd(gcntD + tid, histD[tid]) : 0;
    gbS[tid] = histS[tid] ? atomicAdd(gcntS + tid, histS[tid]) : 0;
  }
  __syncthreads();
  // ---- stage & flush dst-list (bin = dst>>9 from the record itself)
  #pragma unroll
  for (int j = 0; j < 4; ++j)
    if (dd[j] >= 0) stg[pfxD[dd[j] >> BIN_SH] + slotD[j]] = (uint2){recw[j], (unsigned)dd[j]};
  __syncthreads();
  int tot = pfxD[NBIN - 1] + histD[NBIN - 1];
  for (int i = tid; i < tot; i += TPB_A) {
    uint2 r = stg[i];
    int b = (int)(r.y >> BIN_SH);
    int pos = gbD[b] + (i - pfxD[b]);
    if (pos < CAPD) listD[(size_t)b * CAPD + pos] = r;
  }
  __syncthreads();
  // ---- stage & flush src-list {src, w_f32} (exact f32 weight for deg; bin = src>>9)
  #pragma unroll
  for (int j = 0; j < 4; ++j)
    if (ss[j] >= 0) {
      union { float f; unsigned u; } cv; cv.f = wv[j];
      stg[pfxS[ss[j] >> BIN_SH] + slotS[j]] = (uint2){(unsigned)ss[j], cv.u};
    }
  __syncthreads();
  int totS = pfxS[NBIN - 1] + histS[NBIN - 1];
  for (int i = tid; i < totS; i += TPB_A) {
    uint2 r = stg[i];
    int b = (int)(r.x >> BIN_SH);
    int pos = gbS[b] + (i - pfxS[b]);
    if (pos < CAPS) listS[(size_t)b * CAPS + pos] = r;
  }
}

// kaux: three independent jobs merged for concurrency (each alone underfills the machine):
//   blocks [0,NBIN):        deg+dinv+xs from src-bin lists (LDS f32 accumulators)
//   blocks [NBIN,2*NBIN):   bucket-CSR fill from dst-bin lists (LDS slot counters)
//   blocks [2*NBIN,+128):   dense-weight prep (Bt/biasM/BtL/biasL)
__global__ __launch_bounds__(1024) void kaux(
    const int* __restrict__ gcntS, const uint2* __restrict__ listS,
    const float* __restrict__ x, float* __restrict__ dinv, u16* __restrict__ xs,
    const int* __restrict__ gcntD, const uint2* __restrict__ listD,
    unsigned* __restrict__ bkt, int* __restrict__ cnt,
    const float* __restrict__ Wxz, const float* __restrict__ Wxh,
    const float* __restrict__ bxz, const float* __restrict__ bhz,
    const float* __restrict__ bxh, const float* __restrict__ bhh,
    const float* __restrict__ Wlin, const float* __restrict__ blin,
    u16* __restrict__ Bt, float* __restrict__ biasM,
    u16* __restrict__ BtL, float* __restrict__ biasL) {
  __shared__ int smem[512];
  int b = blockIdx.x, tid = threadIdx.x;
  if (b < NBIN) {
    // ---- deg + dinv + xs (validated round 4/5)
    float* acc = (float*)smem;
    if (tid < 512) acc[tid] = 0.f;
    __syncthreads();
    int m = gcntS[b]; if (m > CAPS) m = CAPS;
    const uint2* lp = listS + (size_t)b * CAPS;
    for (int i = tid; i < m; i += 1024) {
      uint2 r = lp[i];
      union { unsigned u; float f; } cv; cv.u = r.y;
      atomicAdd(&acc[r.x & 511], cv.f);
    }
    __syncthreads();
    float dv = 0.f, sc = 1.f;
    if (tid < 512) {
      float d = acc[tid];
      dv = (d > 0.f) ? rsqrtf(d) : 0.f;
      sc = (d > 0.f) ? dv : 1.0f;
    }
    __syncthreads();
    if (tid < 512) {
      acc[tid] = sc;
      int n = b * 512 + tid;
      if (n < N_) dinv[n] = dv;
    }
    __syncthreads();
    int nbase = b * 512;
    for (int i = tid; i < 8192; i += 1024) {   // 512 nodes x 16 float4
      int nl = i >> 4, q = i & 15;
      int n = nbase + nl;
      if (n >= N_) break;                      // nl monotone per thread
      float4 xv = ((const float4*)x)[(size_t)n * 16 + q];
      float s = acc[nl];
      ushort4 ov = { f2bf(xv.x * s), f2bf(xv.y * s), f2bf(xv.z * s), f2bf(xv.w * s) };
      ((ushort4*)xs)[(size_t)n * 16 + q] = ov;
    }
  } else if (b < 2 * NBIN) {
    // ---- bucket-CSR fill (bin's 96KB region stays L2-hot); cnt written coalesced
    int bb = b - NBIN;
    int* lcnt = smem;
    if (tid < 512) lcnt[tid] = 0;
    __syncthreads();
    int m = gcntD[bb]; if (m > CAPD) m = CAPD;
    const uint2* lp = listD + (size_t)bb * CAPD;
    for (int i = tid; i < m; i += 1024) {
      uint2 r = lp[i];
      int node = (int)r.y;
      int s = atomicAdd(&lcnt[node & 511], 1);
      if (s < BKT) bkt[(size_t)node * BKT + s] = r.x;
    }
    __syncthreads();
    int n = bb * 512 + tid;
    if (tid < 512 && n < N_) cnt[n] = lcnt[tid];
  } else {
    // ---- combined dense weights: Bt[n][k], n<64 z-branch else h-branch;
    // k<64 -> W[0]-W[2] (Tx2=2S-x fold), k<128 -> W[1], else 2*W[2].
    int n = b - 2 * NBIN, c = n & 63;
    const float* W = (n < 64) ? Wxz : Wxh;
    if (tid < 192) {
      int k = tid; float v;
      if (k < 64)       v = W[k*64 + c] - W[2*4096 + k*64 + c];
      else if (k < 128) v = W[4096 + (k-64)*64 + c];
      else              v = 2.0f * W[2*4096 + (k-128)*64 + c];
      Bt[n*200 + k] = f2bf(v);
    } else if (tid < 200) Bt[n*200 + tid] = 0;
    if (tid == 0) biasM[n] = (n < 64) ? (bxz[c] + bhz[c]) : (bxh[c] + bhh[c]);
    if (n < 64) {
      if (tid < 64)      BtL[n*72 + tid] = f2bf(Wlin[tid*64 + n]);
      else if (tid < 72) BtL[n*72 + tid] = 0;
      if (tid == 0)      biasL[n] = blin[n];
    }
  }
}

// out[n] = scale(n) * sum_e ew_e * src[s_e], 2 nodes/wave (32 lanes, lane = u32 feature pair).
// mode=1: scale = -dinv[n]^2 (writes scaled Tx1s); mode=0: scale = -dinv[n] (writes S).
// 6250 blocks -> 25k independent half-waves: latency hidden by TLP (round-4 lesson: the
// per-bin LDS-accumulate variant serializes and is 7x slower).
__global__ __launch_bounds__(256) void kgather(
    const u16* __restrict__ srcp, const int* __restrict__ cnt, const float* __restrict__ dinv,
    const unsigned* __restrict__ bkt, u16* __restrict__ dstp, int mode) {
  int n = blockIdx.x * 8 + (threadIdx.x >> 5);
  if (n >= N_) return;
  int li = threadIdx.x & 31;
  int c = cnt[n]; c = (c > BKT) ? BKT : c;
  const unsigned* recs = bkt + (size_t)n * BKT;
  float a0 = 0.f, a1 = 0.f, b0 = 0.f, b1 = 0.f, c0 = 0.f, c1 = 0.f, d0 = 0.f, d1 = 0.f;
  int j = 0;
  for (; j + 3 < c; j += 4) {
    unsigned r0 = recs[j], r1 = recs[j + 1], r2 = recs[j + 2], r3 = recs[j + 3];
    float w0 = bf2f((u16)(r0 >> 16)), w1 = bf2f((u16)(r1 >> 16));
    float w2 = bf2f((u16)(r2 >> 16)), w3 = bf2f((u16)(r3 >> 16));
    unsigned p0 = *(const unsigned*)(srcp + (size_t)(r0 & 0xffffu) * 64 + li * 2);
    unsigned p1 = *(const unsigned*)(srcp + (size_t)(r1 & 0xffffu) * 64 + li * 2);
    unsigned p2 = *(const unsigned*)(srcp + (size_t)(r2 & 0xffffu) * 64 + li * 2);
    unsigned p3 = *(const unsigned*)(srcp + (size_t)(r3 & 0xffffu) * 64 + li * 2);
    a0 += w0 * bf2f((u16)p0); a1 += w0 * bf2f((u16)(p0 >> 16));
    b0 += w1 * bf2f((u16)p1); b1 += w1 * bf2f((u16)(p1 >> 16));
    c0 += w2 * bf2f((u16)p2); c1 += w2 * bf2f((u16)(p2 >> 16));
    d0 += w3 * bf2f((u16)p3); d1 += w3 * bf2f((u16)(p3 >> 16));
  }
  for (; j < c; ++j) {
    unsigned r0 = recs[j];
    float w0 = bf2f((u16)(r0 >> 16));
    unsigned p0 = *(const unsigned*)(srcp + (size_t)(r0 & 0xffffu) * 64 + li * 2);
    a0 += w0 * bf2f((u16)p0); a1 += w0 * bf2f((u16)(p0 >> 16));
  }
  a0 += b0; c0 += d0; a0 += c0;
  a1 += b1; c1 += d1; a1 += c1;
  float dv = dinv[n];
  float sc = mode ? (-dv * dv) : (-dv);
  a0 *= sc; a1 *= sc;
  unsigned outw = (unsigned)f2bf(a0) | ((unsigned)f2bf(a1) << 16);
  *(unsigned*)(dstp + (size_t)n * 64 + li * 2) = outw;
}

// Pure dense: 128 rows/block. [128x192]@[192x128] -> gate -> [128x64]@[64x64] -> out.
// mfma_f32_16x16x32_bf16: A[m=lane&15][k=quad*8+j], B[k][n=lane&15], D col=lane&15,row=quad*4+reg
// x and Tx1 features reconstructed from scaled arrays via rc = 1/dinv (rc=1 for dinv==0,
// where xs holds plain x and Tx1s==0 -- exact). S rows dense, stride 64.
__global__ __launch_bounds__(256) void kgemm(
    const u16* __restrict__ xs, const u16* __restrict__ Tx1s, const u16* __restrict__ Sb,
    const float* __restrict__ dinv,
    const u16* __restrict__ Bt, const float* __restrict__ biasM,
    const u16* __restrict__ BtL, const float* __restrict__ biasL,
    float* __restrict__ out) {
  __shared__ __align__(16) u16 sBt[25600];  // phase1: Bt 128x200 (51200B); phase2: H 128x72 @0 | BtL @9216
  int tid = threadIdx.x, wave = tid >> 6, lane = tid & 63;
  int m16 = lane & 15, quad = lane >> 4;
  int row_base = blockIdx.x * 128;

  for (int i = tid; i < 3200; i += 256)
    ((uint4*)sBt)[i] = ((const uint4*)Bt)[i];

  short8 a[2][6];
  #pragma unroll
  for (int h = 0; h < 2; ++h) {
    int r = row_base + (wave * 2 + h) * 16 + m16;
    if (r < N_) {
      float dv = dinv[r];
      float rc = (dv > 0.f) ? (1.0f / dv) : 1.0f;
      const u16* xr = xs   + (size_t)r * 64;
      const u16* tr = Tx1s + (size_t)r * 64;
      const u16* sr = Sb   + (size_t)r * 64;
      a[h][0] = scale8(*(const short8*)(xr + quad * 8), rc);
      a[h][1] = scale8(*(const short8*)(xr + 32 + quad * 8), rc);
      a[h][2] = scale8(*(const short8*)(tr + quad * 8), rc);
      a[h][3] = scale8(*(const short8*)(tr + 32 + quad * 8), rc);
      a[h][4] = *(const short8*)(sr + quad * 8);
      a[h][5] = *(const short8*)(sr + 32 + quad * 8);
    } else {
      short8 z = {0,0,0,0,0,0,0,0};
      #pragma unroll
      for (int s = 0; s < 6; ++s) a[h][s] = z;
    }
  }
  __syncthreads();

  f32x4 acc[2][8];
  #pragma unroll
  for (int h = 0; h < 2; ++h)
    #pragma unroll
    for (int t = 0; t < 8; ++t) acc[h][t] = (f32x4){0.f, 0.f, 0.f, 0.f};
  #pragma unroll
  for (int t = 0; t < 8; ++t) {
    const u16* brow = sBt + (t * 16 + m16) * 200;
    #pragma unroll
    for (int s = 0; s < 6; ++s) {
      short8 b = *(const short8*)(brow + s * 32 + quad * 8);
      acc[0][t] = __builtin_amdgcn_mfma_f32_16x16x32_bf16(a[0][s], b, acc[0][t], 0, 0, 0);
      acc[1][t] = __builtin_amdgcn_mfma_f32_16x16x32_bf16(a[1][s], b, acc[1][t], 0, 0, 0);
    }
  }
  __syncthreads();

  // gate: H = relu( tanh(hpre) * (1 - sigmoid(zpre)) ) -> bf16 rows @ sBt, stride 72
  #pragma unroll
  for (int h = 0; h < 2; ++h) {
    #pragma unroll
    for (int t = 0; t < 4; ++t) {
      int c = t * 16 + m16;
      float bz = biasM[c], bh = biasM[64 + c];
      #pragma unroll
      for (int rr = 0; rr < 4; ++rr) {
        float z  = acc[h][t][rr] + bz;
        float hp = acc[h][t + 4][rr] + bh;
        float th = 1.0f - 2.0f / (__expf(2.0f * hp) + 1.0f);
        float hv = th / (1.0f + __expf(z));
        hv = fmaxf(hv, 0.0f);
        sBt[((wave * 2 + h) * 16 + quad * 4 + rr) * 72 + c] = f2bf(hv);
      }
    }
  }
  for (int i = tid; i < 576; i += 256)
    ((uint4*)(sBt + 9216))[i] = ((const uint4*)BtL)[i];
  __syncthreads();

  short8 a2[2][2];
  #pragma unroll
  for (int h = 0; h < 2; ++h) {
    const u16* hrow = sBt + ((wave * 2 + h) * 16 + m16) * 72;
    a2[h][0] = *(const short8*)(hrow + quad * 8);
    a2[h][1] = *(const short8*)(hrow + 32 + quad * 8);
  }
  f32x4 acc2[2][4];
  #pragma unroll
  for (int h = 0; h < 2; ++h)
    #pragma unroll
    for (int t = 0; t < 4; ++t) acc2[h][t] = (f32x4){0.f, 0.f, 0.f, 0.f};
  #pragma unroll
  for (int t = 0; t < 4; ++t) {
    const u16* brow = sBt + 9216 + (t * 16 + m16) * 72;
    short8 b0 = *(const short8*)(brow + quad * 8);
    short8 b1 = *(const short8*)(brow + 32 + quad * 8);
    #pragma unroll
    for (int h = 0; h < 2; ++h) {
      acc2[h][t] = __builtin_amdgcn_mfma_f32_16x16x32_bf16(a2[h][0], b0, acc2[h][t], 0, 0, 0);
      acc2[h][t] = __builtin_amdgcn_mfma_f32_16x16x32_bf16(a2[h][1], b1, acc2[h][t], 0, 0, 0);
    }
  }
  #pragma unroll
  for (int h = 0; h < 2; ++h) {
    #pragma unroll
    for (int t = 0; t < 4; ++t) {
      int c = t * 16 + m16;
      float bl = biasL[c];
      #pragma unroll
      for (int rr = 0; rr < 4; ++rr) {
        int nr = row_base + (wave * 2 + h) * 16 + quad * 4 + rr;
        if (nr < N_) out[(size_t)nr * 64 + c] = acc2[h][t][rr] + bl;
      }
    }
  }
}

extern "C" void kernel_launch(void* const* d_in, const int* in_sizes, int n_in,
                              void* d_out, int out_size, void* d_ws, size_t ws_size,
                              hipStream_t stream) {
  const float* x    = (const float*)d_in[0];
  const int*   ei   = (const int*)d_in[1];
  const float* ew   = (const float*)d_in[2];
  const float* Wxz  = (const float*)d_in[3];
  const float* bxz  = (const float*)d_in[4];
  const float* bhz  = (const float*)d_in[6];
  const float* Wxh  = (const float*)d_in[11];
  const float* bxh  = (const float*)d_in[12];
  const float* bhh  = (const float*)d_in[14];
  const float* Wlin = (const float*)d_in[15];
  const float* blin = (const float*)d_in[16];
  float* out = (float*)d_out;

  char* ws = (char*)d_ws;
  float*    dinv  = (float*)   (ws + B_DINV);
  int*      cnt   = (int*)     (ws + B_CNT);
  unsigned* bkt   = (unsigned*)(ws + B_BKT);
  u16*      xsb   = (u16*)     (ws + B_XS);
  u16*      Tx1s  = (u16*)     (ws + B_TX1S);
  u16*      Sb    = (u16*)     (ws + B_S);
  uint2*    listD = (uint2*)   (ws + B_LISTD);
  uint2*    listS = (uint2*)   (ws + B_LISTS);
  int*      gcntD = (int*)     (ws + B_GCNTD);
  int*      gcntS = (int*)     (ws + B_GCNTS);
  u16*      Bt    = (u16*)     (ws + B_BT);
  float*    biasM = (float*)   (ws + B_BIASM);
  u16*      BtL   = (u16*)     (ws + B_BTL);
  float*    biasL = (float*)   (ws + B_BIASL);

  hipMemsetAsync(ws + B_GCNTD, 0, 1024, stream);   // gcntD + gcntS (contiguous)
  kbinA  <<<(E_ + EPB_A - 1) / EPB_A, TPB_A, 0, stream>>>(ei, ew, gcntD, gcntS, listD, listS);
  kaux   <<<GAUX, 1024, 0, stream>>>(gcntS, listS, x, dinv, xsb,
                                     gcntD, listD, bkt, cnt,
                                     Wxz, Wxh, bxz, bhz, bxh, bhh, Wlin, blin,
                                     Bt, biasM, BtL, biasL);
  kgather<<<(N_ + 7) / 8, 256, 0, stream>>>(xsb,  cnt, dinv, bkt, Tx1s, 1);  // Tx1s = -dinv^2 * G1
  kgather<<<(N_ + 7) / 8, 256, 0, stream>>>(Tx1s, cnt, dinv, bkt, Sb,   0);  // S    = -dinv   * G2
  kgemm  <<<(N_ + 127) / 128, 256, 0, stream>>>(xsb, Tx1s, Sb, dinv, Bt, biasM, BtL, biasL, out);
}

// Round 7
// 181.241 us; speedup vs baseline: 4.6861x; 1.0558x over previous
//
#include <hip/hip_runtime.h>

#define N_  50000
#define E_  800000
#define BKT 48         // bucket capacity per node (Poisson(16): P(deg>=48)~1e-9)
#define NBIN 98        // bins of 512 nodes: (50000+511)/512
#define BIN_SH 9
#define CAPD 12032     // records per dst-bin list (mean 8192, +42 sigma)
#define CAPS 12032     // records per src-bin list
#define TPB_A 1024     // kbinA threads/block
#define EPB_A 4096     // kbinA edges/block (4 per thread)
#define GAUX (2 * NBIN + 128)   // kaux grid: deg bins | fill bins | prep blocks

typedef unsigned short u16;
typedef short short8 __attribute__((ext_vector_type(8)));
typedef float f32x4  __attribute__((ext_vector_type(4)));

// workspace byte offsets (256-aligned). ws_size = 256 MiB (per harness poison) -> no overlays.
#define B_DINV   0u          // N f32: dinv (written wholesale by kaux/deg)
#define B_CNT    200192u     // N i32: per-dst edge count (written wholesale by kaux/fill)
#define B_BKT    400384u     // N x BKT u32 records {ew_bf16<<16 | src}, stride 192B
#define B_XS     10000384u   // N*64 bf16: xs = dinv*x (plain x where dinv==0)
#define B_TX1S   16400384u   // N*64 bf16: Tx1s = dinv^2 * (-G1)
#define B_S      22800384u   // N*64 bf16: S = -dinv * G2 (dense, stride 64)
#define B_LISTD  29200384u   // NBIN x CAPD x 8B dst-bin lists {src|ew_bf16<<16, dst}
#define B_LISTS  38633472u   // NBIN x CAPS x 8B src-bin lists {src, w_f32}
#define B_GCNTD  48066560u   // NBIN i32 global dst-bin counters
#define B_GCNTS  48067072u   // NBIN i32 global src-bin counters
#define B_BT     48067584u   // 128 x 200 bf16 combined dense weights (transposed)
#define B_BIASM  48118784u   // 128 f32
#define B_BTL    48119296u   // 64 x 72 bf16 W_lin^T
#define B_BIASL  48128512u   // 64 f32

__device__ __forceinline__ float bf2f(u16 u) {
  union { unsigned int i; float f; } v; v.i = ((unsigned int)u) << 16; return v.f;
}
__device__ __forceinline__ u16 f2bf(float f) {
  union { float f; unsigned int i; } v; v.f = f;
  unsigned int r = v.i + 0x7fffu + ((v.i >> 16) & 1u);  // RNE, finite only
  return (u16)(r >> 16);
}
__device__ __forceinline__ short8 scale8(short8 v, float sc) {
  short8 r;
  #pragma unroll
  for (int i = 0; i < 8; ++i) r[i] = (short)f2bf(bf2f((u16)v[i]) * sc);
  return r;
}

// Phase A: coalesced edge read; dual binning (dst-bin for bucket CSR, src-bin for deg) via
// LDS histograms + prefix scan + dual 32KB LDS staging buffers (wave-limited at 2 blk/CU, so
// 64KB staging is occupancy-free); both lists staged then flushed after ONE barrier.
// Flush bin recovered from the record itself (no binary search).
__global__ __launch_bounds__(1024) void kbinA(const int* __restrict__ ei,
                                              const float* __restrict__ ew,
                                              int* gcntD, int* gcntS,
                                              uint2* listD, uint2* listS) {
  __shared__ int histD[NBIN], pfxD[NBIN], gbD[NBIN];
  __shared__ int histS[NBIN], pfxS[NBIN], gbS[NBIN];
  __shared__ __align__(16) uint2 stgD[EPB_A];
  __shared__ __align__(16) uint2 stgS[EPB_A];
  int tid = threadIdx.x;
  if (tid < NBIN) { histD[tid] = 0; histS[tid] = 0; }
  __syncthreads();
  int base = blockIdx.x * EPB_A + tid;
  unsigned recw[4]; int dd[4], ss[4], slotD[4], slotS[4]; float wv[4];
  #pragma unroll
  for (int j = 0; j < 4; ++j) {
    int e = base + j * TPB_A;
    if (e < E_) {
      int s = ei[e], d = ei[E_ + e];
      float w = ew[e];
      recw[j] = (unsigned)s | ((unsigned)f2bf(w) << 16);
      wv[j] = w; dd[j] = d; ss[j] = s;
      slotD[j] = atomicAdd(&histD[d >> BIN_SH], 1);  // LDS return-atomic
      slotS[j] = atomicAdd(&histS[s >> BIN_SH], 1);
    } else { dd[j] = -1; ss[j] = -1; }
  }
  __syncthreads();
  if (tid < NBIN) {  // exclusive scan (all-broadcast LDS reads) + global reserve
    int sD = 0, sS = 0;
    for (int j = 0; j < tid; ++j) { sD += histD[j]; sS += histS[j]; }
    pfxD[tid] = sD; pfxS[tid] = sS;
    gbD[tid] = histD[tid] ? atomicAdd(gcntD + tid, histD[tid]) : 0;
    gbS[tid] = histS[tid] ? atomicAdd(gcntS + tid, histS[tid]) : 0;
  }
  __syncthreads();
  // ---- stage both lists
  #pragma unroll
  for (int j = 0; j < 4; ++j)
    if (dd[j] >= 0) {
      stgD[pfxD[dd[j] >> BIN_SH] + slotD[j]] = (uint2){recw[j], (unsigned)dd[j]};
      union { float f; unsigned u; } cv; cv.f = wv[j];
      stgS[pfxS[ss[j] >> BIN_SH] + slotS[j]] = (uint2){(unsigned)ss[j], cv.u};
    }
  __syncthreads();
  // ---- flush both (wave-coalesced; bin from record)
  int tot  = pfxD[NBIN - 1] + histD[NBIN - 1];
  int totS = pfxS[NBIN - 1] + histS[NBIN - 1];
  for (int i = tid; i < tot; i += TPB_A) {
    uint2 r = stgD[i];
    int b = (int)(r.y >> BIN_SH);
    int pos = gbD[b] + (i - pfxD[b]);
    if (pos < CAPD) listD[(size_t)b * CAPD + pos] = r;
  }
  for (int i = tid; i < totS; i += TPB_A) {
    uint2 r = stgS[i];
    int b = (int)(r.x >> BIN_SH);
    int pos = gbS[b] + (i - pfxS[b]);
    if (pos < CAPS) listS[(size_t)b * CAPS + pos] = r;
  }
}

// kaux: three independent jobs merged for concurrency (each alone underfills the machine):
//   blocks [0,NBIN):        deg+dinv+xs from src-bin lists (LDS f32 accumulators)
//   blocks [NBIN,2*NBIN):   bucket-CSR fill from dst-bin lists (LDS slot counters)
//   blocks [2*NBIN,+128):   dense-weight prep (Bt/biasM/BtL/biasL)
__global__ __launch_bounds__(1024) void kaux(
    const int* __restrict__ gcntS, const uint2* __restrict__ listS,
    const float* __restrict__ x, float* __restrict__ dinv, u16* __restrict__ xs,
    const int* __restrict__ gcntD, const uint2* __restrict__ listD,
    unsigned* __restrict__ bkt, int* __restrict__ cnt,
    const float* __restrict__ Wxz, const float* __restrict__ Wxh,
    const float* __restrict__ bxz, const float* __restrict__ bhz,
    const float* __restrict__ bxh, const float* __restrict__ bhh,
    const float* __restrict__ Wlin, const float* __restrict__ blin,
    u16* __restrict__ Bt, float* __restrict__ biasM,
    u16* __restrict__ BtL, float* __restrict__ biasL) {
  __shared__ int smem[512];
  int b = blockIdx.x, tid = threadIdx.x;
  if (b < NBIN) {
    // ---- deg + dinv + xs (validated round 4/5)
    float* acc = (float*)smem;
    if (tid < 512) acc[tid] = 0.f;
    __syncthreads();
    int m = gcntS[b]; if (m > CAPS) m = CAPS;
    const uint2* lp = listS + (size_t)b * CAPS;
    for (int i = tid; i < m; i += 1024) {
      uint2 r = lp[i];
      union { unsigned u; float f; } cv; cv.u = r.y;
      atomicAdd(&acc[r.x & 511], cv.f);
    }
    __syncthreads();
    float dv = 0.f, sc = 1.f;
    if (tid < 512) {
      float d = acc[tid];
      dv = (d > 0.f) ? rsqrtf(d) : 0.f;
      sc = (d > 0.f) ? dv : 1.0f;
    }
    __syncthreads();
    if (tid < 512) {
      acc[tid] = sc;
      int n = b * 512 + tid;
      if (n < N_) dinv[n] = dv;
    }
    __syncthreads();
    int nbase = b * 512;
    for (int i = tid; i < 8192; i += 1024) {   // 512 nodes x 16 float4
      int nl = i >> 4, q = i & 15;
      int n = nbase + nl;
      if (n >= N_) break;                      // nl monotone per thread
      float4 xv = ((const float4*)x)[(size_t)n * 16 + q];
      float s = acc[nl];
      ushort4 ov = { f2bf(xv.x * s), f2bf(xv.y * s), f2bf(xv.z * s), f2bf(xv.w * s) };
      ((ushort4*)xs)[(size_t)n * 16 + q] = ov;
    }
  } else if (b < 2 * NBIN) {
    // ---- bucket-CSR fill (bin's 96KB region stays L2-hot); cnt written coalesced
    int bb = b - NBIN;
    int* lcnt = smem;
    if (tid < 512) lcnt[tid] = 0;
    __syncthreads();
    int m = gcntD[bb]; if (m > CAPD) m = CAPD;
    const uint2* lp = listD + (size_t)bb * CAPD;
    for (int i = tid; i < m; i += 1024) {
      uint2 r = lp[i];
      int node = (int)r.y;
      int s = atomicAdd(&lcnt[node & 511], 1);
      if (s < BKT) bkt[(size_t)node * BKT + s] = r.x;
    }
    __syncthreads();
    int n = bb * 512 + tid;
    if (tid < 512 && n < N_) cnt[n] = lcnt[tid];
  } else {
    // ---- combined dense weights: Bt[n][k], n<64 z-branch else h-branch;
    // k<64 -> W[0]-W[2] (Tx2=2S-x fold), k<128 -> W[1], else 2*W[2].
    int n = b - 2 * NBIN, c = n & 63;
    const float* W = (n < 64) ? Wxz : Wxh;
    if (tid < 192) {
      int k = tid; float v;
      if (k < 64)       v = W[k*64 + c] - W[2*4096 + k*64 + c];
      else if (k < 128) v = W[4096 + (k-64)*64 + c];
      else              v = 2.0f * W[2*4096 + (k-128)*64 + c];
      Bt[n*200 + k] = f2bf(v);
    } else if (tid < 200) Bt[n*200 + tid] = 0;
    if (tid == 0) biasM[n] = (n < 64) ? (bxz[c] + bhz[c]) : (bxh[c] + bhh[c]);
    if (n < 64) {
      if (tid < 64)      BtL[n*72 + tid] = f2bf(Wlin[tid*64 + n]);
      else if (tid < 72) BtL[n*72 + tid] = 0;
      if (tid == 0)      biasL[n] = blin[n];
    }
  }
}

// out[n] = scale(n) * sum_e ew_e * src[s_e]. 4 nodes/wave (16 lanes/node, ushort4=8B loads):
// halves issued instructions per edge vs 2-node/dword variant (feature loads AND record
// loads service 2x the edges per instruction); line traffic unchanged (2 lines/row).
// mode=1: scale = -dinv[n]^2 (writes Tx1s); mode=0: scale = -dinv[n] (writes S).
__global__ __launch_bounds__(256) void kgather(
    const u16* __restrict__ srcp, const int* __restrict__ cnt, const float* __restrict__ dinv,
    const unsigned* __restrict__ bkt, u16* __restrict__ dstp, int mode) {
  int n = blockIdx.x * 16 + (threadIdx.x >> 4);
  if (n >= N_) return;
  int li = threadIdx.x & 15;                 // features [li*4, li*4+4)
  int c = cnt[n]; c = (c > BKT) ? BKT : c;
  const unsigned* recs = bkt + (size_t)n * BKT;
  float a0=0.f,a1=0.f,a2=0.f,a3=0.f, b0=0.f,b1=0.f,b2=0.f,b3=0.f;
  float c0=0.f,c1=0.f,c2=0.f,c3=0.f, d0=0.f,d1=0.f,d2=0.f,d3=0.f;
  int j = 0;
  for (; j + 3 < c; j += 4) {
    unsigned r0 = recs[j], r1 = recs[j + 1], r2 = recs[j + 2], r3 = recs[j + 3];
    float w0 = bf2f((u16)(r0 >> 16)), w1 = bf2f((u16)(r1 >> 16));
    float w2 = bf2f((u16)(r2 >> 16)), w3 = bf2f((u16)(r3 >> 16));
    ushort4 p0 = *(const ushort4*)(srcp + (size_t)(r0 & 0xffffu) * 64 + li * 4);
    ushort4 p1 = *(const ushort4*)(srcp + (size_t)(r1 & 0xffffu) * 64 + li * 4);
    ushort4 p2 = *(const ushort4*)(srcp + (size_t)(r2 & 0xffffu) * 64 + li * 4);
    ushort4 p3 = *(const ushort4*)(srcp + (size_t)(r3 & 0xffffu) * 64 + li * 4);
    a0 += w0 * bf2f(p0.x); a1 += w0 * bf2f(p0.y); a2 += w0 * bf2f(p0.z); a3 += w0 * bf2f(p0.w);
    b0 += w1 * bf2f(p1.x); b1 += w1 * bf2f(p1.y); b2 += w1 * bf2f(p1.z); b3 += w1 * bf2f(p1.w);
    c0 += w2 * bf2f(p2.x); c1 += w2 * bf2f(p2.y); c2 += w2 * bf2f(p2.z); c3 += w2 * bf2f(p2.w);
    d0 += w3 * bf2f(p3.x); d1 += w3 * bf2f(p3.y); d2 += w3 * bf2f(p3.z); d3 += w3 * bf2f(p3.w);
  }
  for (; j < c; ++j) {
    unsigned r0 = recs[j];
    float w0 = bf2f((u16)(r0 >> 16));
    ushort4 p0 = *(const ushort4*)(srcp + (size_t)(r0 & 0xffffu) * 64 + li * 4);
    a0 += w0 * bf2f(p0.x); a1 += w0 * bf2f(p0.y); a2 += w0 * bf2f(p0.z); a3 += w0 * bf2f(p0.w);
  }
  a0 += b0; c0 += d0; a0 += c0;
  a1 += b1; c1 += d1; a1 += c1;
  a2 += b2; c2 += d2; a2 += c2;
  a3 += b3; c3 += d3; a3 += c3;
  float dv = dinv[n];
  float sc = mode ? (-dv * dv) : (-dv);
  ushort4 ov = { f2bf(a0 * sc), f2bf(a1 * sc), f2bf(a2 * sc), f2bf(a3 * sc) };
  *(ushort4*)(dstp + (size_t)n * 64 + li * 4) = ov;
}

// Pure dense: 128 rows/block. [128x192]@[192x128] -> gate -> [128x64]@[64x64] -> out.
// mfma_f32_16x16x32_bf16: A[m=lane&15][k=quad*8+j], B[k][n=lane&15], D col=lane&15,row=quad*4+reg
// x and Tx1 features reconstructed from scaled arrays via rc = 1/dinv (rc=1 for dinv==0,
// where xs holds plain x and Tx1s==0 -- exact). S rows dense, stride 64.
__global__ __launch_bounds__(256) void kgemm(
    const u16* __restrict__ xs, const u16* __restrict__ Tx1s, const u16* __restrict__ Sb,
    const float* __restrict__ dinv,
    const u16* __restrict__ Bt, const float* __restrict__ biasM,
    const u16* __restrict__ BtL, const float* __restrict__ biasL,
    float* __restrict__ out) {
  __shared__ __align__(16) u16 sBt[25600];  // phase1: Bt 128x200 (51200B); phase2: H 128x72 @0 | BtL @9216
  int tid = threadIdx.x, wave = tid >> 6, lane = tid & 63;
  int m16 = lane & 15, quad = lane >> 4;
  int row_base = blockIdx.x * 128;

  for (int i = tid; i < 3200; i += 256)
    ((uint4*)sBt)[i] = ((const uint4*)Bt)[i];

  short8 a[2][6];
  #pragma unroll
  for (int h = 0; h < 2; ++h) {
    int r = row_base + (wave * 2 + h) * 16 + m16;
    if (r < N_) {
      float dv = dinv[r];
      float rc = (dv > 0.f) ? (1.0f / dv) : 1.0f;
      const u16* xr = xs   + (size_t)r * 64;
      const u16* tr = Tx1s + (size_t)r * 64;
      const u16* sr = Sb   + (size_t)r * 64;
      a[h][0] = scale8(*(const short8*)(xr + quad * 8), rc);
      a[h][1] = scale8(*(const short8*)(xr + 32 + quad * 8), rc);
      a[h][2] = scale8(*(const short8*)(tr + quad * 8), rc);
      a[h][3] = scale8(*(const short8*)(tr + 32 + quad * 8), rc);
      a[h][4] = *(const short8*)(sr + quad * 8);
      a[h][5] = *(const short8*)(sr + 32 + quad * 8);
    } else {
      short8 z = {0,0,0,0,0,0,0,0};
      #pragma unroll
      for (int s = 0; s < 6; ++s) a[h][s] = z;
    }
  }
  __syncthreads();

  f32x4 acc[2][8];
  #pragma unroll
  for (int h = 0; h < 2; ++h)
    #pragma unroll
    for (int t = 0; t < 8; ++t) acc[h][t] = (f32x4){0.f, 0.f, 0.f, 0.f};
  #pragma unroll
  for (int t = 0; t < 8; ++t) {
    const u16* brow = sBt + (t * 16 + m16) * 200;
    #pragma unroll
    for (int s = 0; s < 6; ++s) {
      short8 b = *(const short8*)(brow + s * 32 + quad * 8);
      acc[0][t] = __builtin_amdgcn_mfma_f32_16x16x32_bf16(a[0][s], b, acc[0][t], 0, 0, 0);
      acc[1][t] = __builtin_amdgcn_mfma_f32_16x16x32_bf16(a[1][s], b, acc[1][t], 0, 0, 0);
    }
  }
  __syncthreads();

  // gate: H = relu( tanh(hpre) * (1 - sigmoid(zpre)) ) -> bf16 rows @ sBt, stride 72
  #pragma unroll
  for (int h = 0; h < 2; ++h) {
    #pragma unroll
    for (int t = 0; t < 4; ++t) {
      int c = t * 16 + m16;
      float bz = biasM[c], bh = biasM[64 + c];
      #pragma unroll
      for (int rr = 0; rr < 4; ++rr) {
        float z  = acc[h][t][rr] + bz;
        float hp = acc[h][t + 4][rr] + bh;
        float th = 1.0f - 2.0f / (__expf(2.0f * hp) + 1.0f);
        float hv = th / (1.0f + __expf(z));
        hv = fmaxf(hv, 0.0f);
        sBt[((wave * 2 + h) * 16 + quad * 4 + rr) * 72 + c] = f2bf(hv);
      }
    }
  }
  for (int i = tid; i < 576; i += 256)
    ((uint4*)(sBt + 9216))[i] = ((const uint4*)BtL)[i];
  __syncthreads();

  short8 a2[2][2];
  #pragma unroll
  for (int h = 0; h < 2; ++h) {
    const u16* hrow = sBt + ((wave * 2 + h) * 16 + m16) * 72;
    a2[h][0] = *(const short8*)(hrow + quad * 8);
    a2[h][1] = *(const short8*)(hrow + 32 + quad * 8);
  }
  f32x4 acc2[2][4];
  #pragma unroll
  for (int h = 0; h < 2; ++h)
    #pragma unroll
    for (int t = 0; t < 4; ++t) acc2[h][t] = (f32x4){0.f, 0.f, 0.f, 0.f};
  #pragma unroll
  for (int t = 0; t < 4; ++t) {
    const u16* brow = sBt + 9216 + (t * 16 + m16) * 72;
    short8 b0 = *(const short8*)(brow + quad * 8);
    short8 b1 = *(const short8*)(brow + 32 + quad * 8);
    #pragma unroll
    for (int h = 0; h < 2; ++h) {
      acc2[h][t] = __builtin_amdgcn_mfma_f32_16x16x32_bf16(a2[h][0], b0, acc2[h][t], 0, 0, 0);
      acc2[h][t] = __builtin_amdgcn_mfma_f32_16x16x32_bf16(a2[h][1], b1, acc2[h][t], 0, 0, 0);
    }
  }
  #pragma unroll
  for (int h = 0; h < 2; ++h) {
    #pragma unroll
    for (int t = 0; t < 4; ++t) {
      int c = t * 16 + m16;
      float bl = biasL[c];
      #pragma unroll
      for (int rr = 0; rr < 4; ++rr) {
        int nr = row_base + (wave * 2 + h) * 16 + quad * 4 + rr;
        if (nr < N_) out[(size_t)nr * 64 + c] = acc2[h][t][rr] + bl;
      }
    }
  }
}

extern "C" void kernel_launch(void* const* d_in, const int* in_sizes, int n_in,
                              void* d_out, int out_size, void* d_ws, size_t ws_size,
                              hipStream_t stream) {
  const float* x    = (const float*)d_in[0];
  const int*   ei   = (const int*)d_in[1];
  const float* ew   = (const float*)d_in[2];
  const float* Wxz  = (const float*)d_in[3];
  const float* bxz  = (const float*)d_in[4];
  const float* bhz  = (const float*)d_in[6];
  const float* Wxh  = (const float*)d_in[11];
  const float* bxh  = (const float*)d_in[12];
  const float* bhh  = (const float*)d_in[14];
  const float* Wlin = (const float*)d_in[15];
  const float* blin = (const float*)d_in[16];
  float* out = (float*)d_out;

  char* ws = (char*)d_ws;
  float*    dinv  = (float*)   (ws + B_DINV);
  int*      cnt   = (int*)     (ws + B_CNT);
  unsigned* bkt   = (unsigned*)(ws + B_BKT);
  u16*      xsb   = (u16*)     (ws + B_XS);
  u16*      Tx1s  = (u16*)     (ws + B_TX1S);
  u16*      Sb    = (u16*)     (ws + B_S);
  uint2*    listD = (uint2*)   (ws + B_LISTD);
  uint2*    listS = (uint2*)   (ws + B_LISTS);
  int*      gcntD = (int*)     (ws + B_GCNTD);
  int*      gcntS = (int*)     (ws + B_GCNTS);
  u16*      Bt    = (u16*)     (ws + B_BT);
  float*    biasM = (float*)   (ws + B_BIASM);
  u16*      BtL   = (u16*)     (ws + B_BTL);
  float*    biasL = (float*)   (ws + B_BIASL);

  hipMemsetAsync(ws + B_GCNTD, 0, 1024, stream);   // gcntD + gcntS (contiguous)
  kbinA  <<<(E_ + EPB_A - 1) / EPB_A, TPB_A, 0, stream>>>(ei, ew, gcntD, gcntS, listD, listS);
  kaux   <<<GAUX, 1024, 0, stream>>>(gcntS, listS, x, dinv, xsb,
                                     gcntD, listD, bkt, cnt,
                                     Wxz, Wxh, bxz, bhz, bxh, bhh, Wlin, blin,
                                     Bt, biasM, BtL, biasL);
  kgather<<<(N_ + 15) / 16, 256, 0, stream>>>(xsb,  cnt, dinv, bkt, Tx1s, 1);  // Tx1s = -dinv^2 * G1
  kgather<<<(N_ + 15) / 16, 256, 0, stream>>>(Tx1s, cnt, dinv, bkt, Sb,   0);  // S    = -dinv   * G2
  kgemm  <<<(N_ + 127) / 128, 256, 0, stream>>>(xsb, Tx1s, Sb, dinv, Bt, biasM, BtL, biasL, out);
}

// Round 8
// 181.155 us; speedup vs baseline: 4.6884x; 1.0005x over previous
//
#include <hip/hip_runtime.h>

#define N_  50000
#define E_  800000
#define BKT 48         // bucket capacity per node (Poisson(16): P(deg>=48)~1e-9)
#define NBIN 98        // bins of 512 nodes: (50000+511)/512
#define BIN_SH 9
#define CAPD 12032     // records per dst-bin list (mean 8192, +42 sigma)
#define CAPS 12032     // records per src-bin list
#define TPB_A 1024     // kbinA threads/block
#define EPB_A 4096     // kbinA edges/block (4 per thread)
#define GAUX (2 * NBIN + 128)   // kaux grid: deg bins | fill bins | prep blocks

typedef unsigned short u16;
typedef short short8 __attribute__((ext_vector_type(8)));
typedef float f32x4  __attribute__((ext_vector_type(4)));

// workspace byte offsets (256-aligned). ws_size = 256 MiB (per harness poison) -> no overlays.
#define B_DINV   0u          // N f32: dinv (written wholesale by kaux/deg)
#define B_CNT    200192u     // N i32: per-dst edge count (written wholesale by kaux/fill)
#define B_BKT    400384u     // N x BKT u32 records {ew_bf16<<16 | src}, stride 192B
#define B_XS     10000384u   // N*64 bf16: xs = dinv*x (plain x where dinv==0; gather input)
#define B_TX1S   16400384u   // N*64 bf16: Tx1s = -dinv^2 * G1 (gather input for pass 2)
#define B_S      22800384u   // N*64 bf16: S = -dinv * G2 (GEMM feature, stride 64)
#define B_LISTD  29200384u   // NBIN x CAPD x 8B dst-bin lists {src|ew_bf16<<16, dst}
#define B_LISTS  38633472u   // NBIN x CAPS x 8B src-bin lists {src, w_f32}
#define B_GCNTD  48066560u   // NBIN i32 global dst-bin counters
#define B_GCNTS  48067072u   // NBIN i32 global src-bin counters
#define B_BT     48067584u   // 128 x 200 bf16 combined dense weights (transposed)
#define B_BIASM  48118784u   // 128 f32
#define B_BTL    48119296u   // 64 x 72 bf16 W_lin^T
#define B_BIASL  48128512u   // 64 f32
#define B_XB     48128768u   // N*64 bf16: xb = plain x (GEMM feature T0)
#define B_TX1U   54528768u   // N*64 bf16: Tx1u = -dinv * G1 (GEMM feature T1)

__device__ __forceinline__ float bf2f(u16 u) {
  union { unsigned int i; float f; } v; v.i = ((unsigned int)u) << 16; return v.f;
}
__device__ __forceinline__ u16 f2bf(float f) {
  union { float f; unsigned int i; } v; v.f = f;
  unsigned int r = v.i + 0x7fffu + ((v.i >> 16) & 1u);  // RNE, finite only
  return (u16)(r >> 16);
}

// Phase A: coalesced edge read; dual binning (dst-bin for bucket CSR, src-bin for deg) via
// LDS histograms + prefix scan + dual 32KB LDS staging buffers; both lists staged then
// flushed after ONE barrier (wave-coalesced). Flush bin recovered from the record itself.
__global__ __launch_bounds__(1024) void kbinA(const int* __restrict__ ei,
                                              const float* __restrict__ ew,
                                              int* gcntD, int* gcntS,
                                              uint2* listD, uint2* listS) {
  __shared__ int histD[NBIN], pfxD[NBIN], gbD[NBIN];
  __shared__ int histS[NBIN], pfxS[NBIN], gbS[NBIN];
  __shared__ __align__(16) uint2 stgD[EPB_A];
  __shared__ __align__(16) uint2 stgS[EPB_A];
  int tid = threadIdx.x;
  if (tid < NBIN) { histD[tid] = 0; histS[tid] = 0; }
  __syncthreads();
  int base = blockIdx.x * EPB_A + tid;
  unsigned recw[4]; int dd[4], ss[4], slotD[4], slotS[4]; float wv[4];
  #pragma unroll
  for (int j = 0; j < 4; ++j) {
    int e = base + j * TPB_A;
    if (e < E_) {
      int s = ei[e], d = ei[E_ + e];
      float w = ew[e];
      recw[j] = (unsigned)s | ((unsigned)f2bf(w) << 16);
      wv[j] = w; dd[j] = d; ss[j] = s;
      slotD[j] = atomicAdd(&histD[d >> BIN_SH], 1);  // LDS return-atomic
      slotS[j] = atomicAdd(&histS[s >> BIN_SH], 1);
    } else { dd[j] = -1; ss[j] = -1; }
  }
  __syncthreads();
  if (tid < NBIN) {  // exclusive scan (all-broadcast LDS reads) + global reserve
    int sD = 0, sS = 0;
    for (int j = 0; j < tid; ++j) { sD += histD[j]; sS += histS[j]; }
    pfxD[tid] = sD; pfxS[tid] = sS;
    gbD[tid] = histD[tid] ? atomicAdd(gcntD + tid, histD[tid]) : 0;
    gbS[tid] = histS[tid] ? atomicAdd(gcntS + tid, histS[tid]) : 0;
  }
  __syncthreads();
  // ---- stage both lists
  #pragma unroll
  for (int j = 0; j < 4; ++j)
    if (dd[j] >= 0) {
      stgD[pfxD[dd[j] >> BIN_SH] + slotD[j]] = (uint2){recw[j], (unsigned)dd[j]};
      union { float f; unsigned u; } cv; cv.f = wv[j];
      stgS[pfxS[ss[j] >> BIN_SH] + slotS[j]] = (uint2){(unsigned)ss[j], cv.u};
    }
  __syncthreads();
  // ---- flush both (wave-coalesced; bin from record)
  int tot  = pfxD[NBIN - 1] + histD[NBIN - 1];
  int totS = pfxS[NBIN - 1] + histS[NBIN - 1];
  for (int i = tid; i < tot; i += TPB_A) {
    uint2 r = stgD[i];
    int b = (int)(r.y >> BIN_SH);
    int pos = gbD[b] + (i - pfxD[b]);
    if (pos < CAPD) listD[(size_t)b * CAPD + pos] = r;
  }
  for (int i = tid; i < totS; i += TPB_A) {
    uint2 r = stgS[i];
    int b = (int)(r.x >> BIN_SH);
    int pos = gbS[b] + (i - pfxS[b]);
    if (pos < CAPS) listS[(size_t)b * CAPS + pos] = r;
  }
}

// kaux: three independent jobs merged for concurrency:
//   blocks [0,NBIN):        deg+dinv+xs+xb from src-bin lists (LDS f32 accumulators)
//   blocks [NBIN,2*NBIN):   bucket-CSR fill from dst-bin lists (LDS slot counters)
//   blocks [2*NBIN,+128):   dense-weight prep (Bt/biasM/BtL/biasL)
__global__ __launch_bounds__(1024) void kaux(
    const int* __restrict__ gcntS, const uint2* __restrict__ listS,
    const float* __restrict__ x, float* __restrict__ dinv,
    u16* __restrict__ xs, u16* __restrict__ xb,
    const int* __restrict__ gcntD, const uint2* __restrict__ listD,
    unsigned* __restrict__ bkt, int* __restrict__ cnt,
    const float* __restrict__ Wxz, const float* __restrict__ Wxh,
    const float* __restrict__ bxz, const float* __restrict__ bhz,
    const float* __restrict__ bxh, const float* __restrict__ bhh,
    const float* __restrict__ Wlin, const float* __restrict__ blin,
    u16* __restrict__ Bt, float* __restrict__ biasM,
    u16* __restrict__ BtL, float* __restrict__ biasL) {
  __shared__ int smem[512];
  int b = blockIdx.x, tid = threadIdx.x;
  if (b < NBIN) {
    // ---- deg + dinv + xs (scaled gather input) + xb (plain bf16 feature)
    float* acc = (float*)smem;
    if (tid < 512) acc[tid] = 0.f;
    __syncthreads();
    int m = gcntS[b]; if (m > CAPS) m = CAPS;
    const uint2* lp = listS + (size_t)b * CAPS;
    for (int i = tid; i < m; i += 1024) {
      uint2 r = lp[i];
      union { unsigned u; float f; } cv; cv.u = r.y;
      atomicAdd(&acc[r.x & 511], cv.f);
    }
    __syncthreads();
    float dv = 0.f, sc = 1.f;
    if (tid < 512) {
      float d = acc[tid];
      dv = (d > 0.f) ? rsqrtf(d) : 0.f;
      sc = (d > 0.f) ? dv : 1.0f;
    }
    __syncthreads();
    if (tid < 512) {
      acc[tid] = sc;
      int n = b * 512 + tid;
      if (n < N_) dinv[n] = dv;
    }
    __syncthreads();
    int nbase = b * 512;
    for (int i = tid; i < 8192; i += 1024) {   // 512 nodes x 16 float4
      int nl = i >> 4, q = i & 15;
      int n = nbase + nl;
      if (n >= N_) break;                      // nl monotone per thread
      float4 xv = ((const float4*)x)[(size_t)n * 16 + q];
      float s = acc[nl];
      ushort4 ov = { f2bf(xv.x * s), f2bf(xv.y * s), f2bf(xv.z * s), f2bf(xv.w * s) };
      ((ushort4*)xs)[(size_t)n * 16 + q] = ov;
      ushort4 ob = { f2bf(xv.x), f2bf(xv.y), f2bf(xv.z), f2bf(xv.w) };
      ((ushort4*)xb)[(size_t)n * 16 + q] = ob;
    }
  } else if (b < 2 * NBIN) {
    // ---- bucket-CSR fill (bin's 96KB region stays L2-hot); cnt written coalesced
    int bb = b - NBIN;
    int* lcnt = smem;
    if (tid < 512) lcnt[tid] = 0;
    __syncthreads();
    int m = gcntD[bb]; if (m > CAPD) m = CAPD;
    const uint2* lp = listD + (size_t)bb * CAPD;
    for (int i = tid; i < m; i += 1024) {
      uint2 r = lp[i];
      int node = (int)r.y;
      int s = atomicAdd(&lcnt[node & 511], 1);
      if (s < BKT) bkt[(size_t)node * BKT + s] = r.x;
    }
    __syncthreads();
    int n = bb * 512 + tid;
    if (tid < 512 && n < N_) cnt[n] = lcnt[tid];
  } else {
    // ---- combined dense weights: Bt[n][k], n<64 z-branch else h-branch;
    // k<64 -> W[0]-W[2] (Tx2=2S-x fold), k<128 -> W[1], else 2*W[2].
    int n = b - 2 * NBIN, c = n & 63;
    const float* W = (n < 64) ? Wxz : Wxh;
    if (tid < 192) {
      int k = tid; float v;
      if (k < 64)       v = W[k*64 + c] - W[2*4096 + k*64 + c];
      else if (k < 128) v = W[4096 + (k-64)*64 + c];
      else              v = 2.0f * W[2*4096 + (k-128)*64 + c];
      Bt[n*200 + k] = f2bf(v);
    } else if (tid < 200) Bt[n*200 + tid] = 0;
    if (tid == 0) biasM[n] = (n < 64) ? (bxz[c] + bhz[c]) : (bxh[c] + bhh[c]);
    if (n < 64) {
      if (tid < 64)      BtL[n*72 + tid] = f2bf(Wlin[tid*64 + n]);
      else if (tid < 72) BtL[n*72 + tid] = 0;
      if (tid == 0)      biasL[n] = blin[n];
    }
  }
}

// out[n] = scale(n) * sum_e ew_e * src[s_e]. 4 nodes/wave (16 lanes/node, ushort4 loads);
// records loaded 4-at-a-time via uint4 (16B-aligned: row base n*192B, j%4==0).
// Pass 1 (dsc!=0): dsc = -dv^2*sum (gather input), dft = -dv*sum (GEMM feature Tx1u).
// Pass 2 (dsc==0): dft = -dv*sum (GEMM feature S).
__global__ __launch_bounds__(256) void kgather(
    const u16* __restrict__ srcp, const int* __restrict__ cnt, const float* __restrict__ dinv,
    const unsigned* __restrict__ bkt, u16* __restrict__ dsc, u16* __restrict__ dft) {
  int n = blockIdx.x * 16 + (threadIdx.x >> 4);
  if (n >= N_) return;
  int li = threadIdx.x & 15;                 // features [li*4, li*4+4)
  int c = cnt[n]; c = (c > BKT) ? BKT : c;
  const unsigned* recs = bkt + (size_t)n * BKT;
  float a0=0.f,a1=0.f,a2=0.f,a3=0.f, b0=0.f,b1=0.f,b2=0.f,b3=0.f;
  float c0=0.f,c1=0.f,c2=0.f,c3=0.f, d0=0.f,d1=0.f,d2=0.f,d3=0.f;
  int j = 0;
  for (; j + 3 < c; j += 4) {
    uint4 rr = *(const uint4*)(recs + j);
    float w0 = bf2f((u16)(rr.x >> 16)), w1 = bf2f((u16)(rr.y >> 16));
    float w2 = bf2f((u16)(rr.z >> 16)), w3 = bf2f((u16)(rr.w >> 16));
    ushort4 p0 = *(const ushort4*)(srcp + (size_t)(rr.x & 0xffffu) * 64 + li * 4);
    ushort4 p1 = *(const ushort4*)(srcp + (size_t)(rr.y & 0xffffu) * 64 + li * 4);
    ushort4 p2 = *(const ushort4*)(srcp + (size_t)(rr.z & 0xffffu) * 64 + li * 4);
    ushort4 p3 = *(const ushort4*)(srcp + (size_t)(rr.w & 0xffffu) * 64 + li * 4);
    a0 += w0 * bf2f(p0.x); a1 += w0 * bf2f(p0.y); a2 += w0 * bf2f(p0.z); a3 += w0 * bf2f(p0.w);
    b0 += w1 * bf2f(p1.x); b1 += w1 * bf2f(p1.y); b2 += w1 * bf2f(p1.z); b3 += w1 * bf2f(p1.w);
    c0 += w2 * bf2f(p2.x); c1 += w2 * bf2f(p2.y); c2 += w2 * bf2f(p2.z); c3 += w2 * bf2f(p2.w);
    d0 += w3 * bf2f(p3.x); d1 += w3 * bf2f(p3.y); d2 += w3 * bf2f(p3.z); d3 += w3 * bf2f(p3.w);
  }
  for (; j < c; ++j) {
    unsigned r0 = recs[j];
    float w0 = bf2f((u16)(r0 >> 16));
    ushort4 p0 = *(const ushort4*)(srcp + (size_t)(r0 & 0xffffu) * 64 + li * 4);
    a0 += w0 * bf2f(p0.x); a1 += w0 * bf2f(p0.y); a2 += w0 * bf2f(p0.z); a3 += w0 * bf2f(p0.w);
  }
  a0 += b0; c0 += d0; a0 += c0;
  a1 += b1; c1 += d1; a1 += c1;
  a2 += b2; c2 += d2; a2 += c2;
  a3 += b3; c3 += d3; a3 += c3;
  float dv = dinv[n];
  float sf = -dv;                            // feature scale
  ushort4 of = { f2bf(a0 * sf), f2bf(a1 * sf), f2bf(a2 * sf), f2bf(a3 * sf) };
  *(ushort4*)(dft + (size_t)n * 64 + li * 4) = of;
  if (dsc) {
    float ss = -dv * dv;                     // gather-input scale
    ushort4 os = { f2bf(a0 * ss), f2bf(a1 * ss), f2bf(a2 * ss), f2bf(a3 * ss) };
    *(ushort4*)(dsc + (size_t)n * 64 + li * 4) = os;
  }
}

// Pure dense: 128 rows/block. [128x192]@[192x128] -> gate -> [128x64]@[64x64] -> out.
// mfma_f32_16x16x32_bf16: A[m=lane&15][k=quad*8+j], B[k][n=lane&15], D col=lane&15,row=quad*4+reg
// Features xb (=x), Tx1u (=-dinv*G1), Sb (=-dinv*G2) are pre-materialized unscaled ->
// zero per-thread rescale VALU work (round-7 finding: scale8 cost ~2x the MFMA time).
__global__ __launch_bounds__(256) void kgemm(
    const u16* __restrict__ xb, const u16* __restrict__ Tx1u, const u16* __restrict__ Sb,
    const u16* __restrict__ Bt, const float* __restrict__ biasM,
    const u16* __restrict__ BtL, const float* __restrict__ biasL,
    float* __restrict__ out) {
  __shared__ __align__(16) u16 sBt[25600];  // phase1: Bt 128x200 (51200B); phase2: H 128x72 @0 | BtL @9216
  int tid = threadIdx.x, wave = tid >> 6, lane = tid & 63;
  int m16 = lane & 15, quad = lane >> 4;
  int row_base = blockIdx.x * 128;

  for (int i = tid; i < 3200; i += 256)
    ((uint4*)sBt)[i] = ((const uint4*)Bt)[i];

  short8 a[2][6];
  #pragma unroll
  for (int h = 0; h < 2; ++h) {
    int r = row_base + (wave * 2 + h) * 16 + m16;
    if (r < N_) {
      const u16* xr = xb   + (size_t)r * 64;
      const u16* tr = Tx1u + (size_t)r * 64;
      const u16* sr = Sb   + (size_t)r * 64;
      a[h][0] = *(const short8*)(xr + quad * 8);
      a[h][1] = *(const short8*)(xr + 32 + quad * 8);
      a[h][2] = *(const short8*)(tr + quad * 8);
      a[h][3] = *(const short8*)(tr + 32 + quad * 8);
      a[h][4] = *(const short8*)(sr + quad * 8);
      a[h][5] = *(const short8*)(sr + 32 + quad * 8);
    } else {
      short8 z = {0,0,0,0,0,0,0,0};
      #pragma unroll
      for (int s = 0; s < 6; ++s) a[h][s] = z;
    }
  }
  __syncthreads();

  f32x4 acc[2][8];
  #pragma unroll
  for (int h = 0; h < 2; ++h)
    #pragma unroll
    for (int t = 0; t < 8; ++t) acc[h][t] = (f32x4){0.f, 0.f, 0.f, 0.f};
  #pragma unroll
  for (int t = 0; t < 8; ++t) {
    const u16* brow = sBt + (t * 16 + m16) * 200;
    #pragma unroll
    for (int s = 0; s < 6; ++s) {
      short8 b = *(const short8*)(brow + s * 32 + quad * 8);
      acc[0][t] = __builtin_amdgcn_mfma_f32_16x16x32_bf16(a[0][s], b, acc[0][t], 0, 0, 0);
      acc[1][t] = __builtin_amdgcn_mfma_f32_16x16x32_bf16(a[1][s], b, acc[1][t], 0, 0, 0);
    }
  }
  __syncthreads();

  // gate: H = relu( tanh(hpre) * (1 - sigmoid(zpre)) ) -> bf16 rows @ sBt, stride 72
  #pragma unroll
  for (int h = 0; h < 2; ++h) {
    #pragma unroll
    for (int t = 0; t < 4; ++t) {
      int c = t * 16 + m16;
      float bz = biasM[c], bh = biasM[64 + c];
      #pragma unroll
      for (int rr = 0; rr < 4; ++rr) {
        float z  = acc[h][t][rr] + bz;
        float hp = acc[h][t + 4][rr] + bh;
        float th = 1.0f - 2.0f / (__expf(2.0f * hp) + 1.0f);
        float hv = th / (1.0f + __expf(z));
        hv = fmaxf(hv, 0.0f);
        sBt[((wave * 2 + h) * 16 + quad * 4 + rr) * 72 + c] = f2bf(hv);
      }
    }
  }
  for (int i = tid; i < 576; i += 256)
    ((uint4*)(sBt + 9216))[i] = ((const uint4*)BtL)[i];
  __syncthreads();

  short8 a2[2][2];
  #pragma unroll
  for (int h = 0; h < 2; ++h) {
    const u16* hrow = sBt + ((wave * 2 + h) * 16 + m16) * 72;
    a2[h][0] = *(const short8*)(hrow + quad * 8);
    a2[h][1] = *(const short8*)(hrow + 32 + quad * 8);
  }
  f32x4 acc2[2][4];
  #pragma unroll
  for (int h = 0; h < 2; ++h)
    #pragma unroll
    for (int t = 0; t < 4; ++t) acc2[h][t] = (f32x4){0.f, 0.f, 0.f, 0.f};
  #pragma unroll
  for (int t = 0; t < 4; ++t) {
    const u16* brow = sBt + 9216 + (t * 16 + m16) * 72;
    short8 b0 = *(const short8*)(brow + quad * 8);
    short8 b1 = *(const short8*)(brow + 32 + quad * 8);
    #pragma unroll
    for (int h = 0; h < 2; ++h) {
      acc2[h][t] = __builtin_amdgcn_mfma_f32_16x16x32_bf16(a2[h][0], b0, acc2[h][t], 0, 0, 0);
      acc2[h][t] = __builtin_amdgcn_mfma_f32_16x16x32_bf16(a2[h][1], b1, acc2[h][t], 0, 0, 0);
    }
  }
  #pragma unroll
  for (int h = 0; h < 2; ++h) {
    #pragma unroll
    for (int t = 0; t < 4; ++t) {
      int c = t * 16 + m16;
      float bl = biasL[c];
      #pragma unroll
      for (int rr = 0; rr < 4; ++rr) {
        int nr = row_base + (wave * 2 + h) * 16 + quad * 4 + rr;
        if (nr < N_) out[(size_t)nr * 64 + c] = acc2[h][t][rr] + bl;
      }
    }
  }
}

extern "C" void kernel_launch(void* const* d_in, const int* in_sizes, int n_in,
                              void* d_out, int out_size, void* d_ws, size_t ws_size,
                              hipStream_t stream) {
  const float* x    = (const float*)d_in[0];
  const int*   ei   = (const int*)d_in[1];
  const float* ew   = (const float*)d_in[2];
  const float* Wxz  = (const float*)d_in[3];
  const float* bxz  = (const float*)d_in[4];
  const float* bhz  = (const float*)d_in[6];
  const float* Wxh  = (const float*)d_in[11];
  const float* bxh  = (const float*)d_in[12];
  const float* bhh  = (const float*)d_in[14];
  const float* Wlin = (const float*)d_in[15];
  const float* blin = (const float*)d_in[16];
  float* out = (float*)d_out;

  char* ws = (char*)d_ws;
  float*    dinv  = (float*)   (ws + B_DINV);
  int*      cnt   = (int*)     (ws + B_CNT);
  unsigned* bkt   = (unsigned*)(ws + B_BKT);
  u16*      xsb   = (u16*)     (ws + B_XS);
  u16*      Tx1s  = (u16*)     (ws + B_TX1S);
  u16*      Sb    = (u16*)     (ws + B_S);
  uint2*    listD = (uint2*)   (ws + B_LISTD);
  uint2*    listS = (uint2*)   (ws + B_LISTS);
  int*      gcntD = (int*)     (ws + B_GCNTD);
  int*      gcntS = (int*)     (ws + B_GCNTS);
  u16*      Bt    = (u16*)     (ws + B_BT);
  float*    biasM = (float*)   (ws + B_BIASM);
  u16*      BtL   = (u16*)     (ws + B_BTL);
  float*    biasL = (float*)   (ws + B_BIASL);
  u16*      xbb   = (u16*)     (ws + B_XB);
  u16*      Tx1u  = (u16*)     (ws + B_TX1U);

  hipMemsetAsync(ws + B_GCNTD, 0, 1024, stream);   // gcntD + gcntS (contiguous)
  kbinA  <<<(E_ + EPB_A - 1) / EPB_A, TPB_A, 0, stream>>>(ei, ew, gcntD, gcntS, listD, listS);
  kaux   <<<GAUX, 1024, 0, stream>>>(gcntS, listS, x, dinv, xsb, xbb,
                                     gcntD, listD, bkt, cnt,
                                     Wxz, Wxh, bxz, bhz, bxh, bhh, Wlin, blin,
                                     Bt, biasM, BtL, biasL);
  kgather<<<(N_ + 15) / 16, 256, 0, stream>>>(xsb,  cnt, dinv, bkt, Tx1s, Tx1u); // pass 1
  kgather<<<(N_ + 15) / 16, 256, 0, stream>>>(Tx1s, cnt, dinv, bkt, 0,    Sb);   // pass 2
  kgemm  <<<(N_ + 127) / 128, 256, 0, stream>>>(xbb, Tx1u, Sb, Bt, biasM, BtL, biasL, out);
}

// Round 9
// 180.175 us; speedup vs baseline: 4.7139x; 1.0054x over previous
//
#include <hip/hip_runtime.h>

#define N_  50000
#define E_  800000
#define BKT 48         // bucket capacity per node (Poisson(16): P(deg>=48)~1e-9)
#define NBIN 98        // bins of 512 nodes: (50000+511)/512
#define BIN_SH 9
#define CAPD 12032     // records per dst-bin list (mean 8192, +42 sigma)
#define CAPS 12032     // records per src-bin list
#define TPB_A 1024     // kbinA threads/block
#define EPB_A 2048     // kbinA edges/block (2 per thread; 391 blocks for machine fill)
#define GAUX (2 * NBIN + 128)   // kaux grid: deg bins | fill bins | prep blocks

typedef unsigned short u16;
typedef short short8 __attribute__((ext_vector_type(8)));
typedef float f32x4  __attribute__((ext_vector_type(4)));

// workspace byte offsets (256-aligned). ws_size = 256 MiB (per harness poison) -> no overlays.
#define B_DINV   0u          // N f32: dinv (written wholesale by kaux/deg)
#define B_CNT    200192u     // N i32: per-dst edge count (written wholesale by kaux/fill)
#define B_BKT    400384u     // N x BKT u32 records {ew_bf16<<16 | src}, stride 192B
#define B_XS     10000384u   // N*64 bf16: xs = dinv*x (plain x where dinv==0; gather input)
#define B_TX1S   16400384u   // N*64 bf16: Tx1s = -dinv^2 * G1 (gather input for pass 2)
#define B_S      22800384u   // N*64 bf16: S = -dinv * G2 (GEMM feature, stride 64)
#define B_LISTD  29200384u   // NBIN x CAPD x 8B dst-bin lists {src|ew_bf16<<16, dst}
#define B_LISTS  38633472u   // NBIN x CAPS x 8B src-bin lists {src, w_f32}
#define B_GCNTD  48066560u   // NBIN i32 global dst-bin counters
#define B_GCNTS  48067072u   // NBIN i32 global src-bin counters
#define B_BT     48067584u   // 128 x 200 bf16 combined dense weights (transposed)
#define B_BIASM  48118784u   // 128 f32
#define B_BTL    48119296u   // 64 x 72 bf16 W_lin^T
#define B_BIASL  48128512u   // 64 f32
#define B_XB     48128768u   // N*64 bf16: xb = plain x (GEMM feature T0)
#define B_TX1U   54528768u   // N*64 bf16: Tx1u = -dinv * G1 (GEMM feature T1)

__device__ __forceinline__ float bf2f(u16 u) {
  union { unsigned int i; float f; } v; v.i = ((unsigned int)u) << 16; return v.f;
}
__device__ __forceinline__ u16 f2bf(float f) {
  union { float f; unsigned int i; } v; v.f = f;
  unsigned int r = v.i + 0x7fffu + ((v.i >> 16) & 1u);  // RNE, finite only
  return (u16)(r >> 16);
}

// Phase A: coalesced edge read; dual binning (dst-bin for bucket CSR, src-bin for deg) via
// LDS histograms + prefix scan + dual 16KB LDS staging buffers; both lists staged then
// flushed after ONE barrier (wave-coalesced). 391 blocks (EPB=2048) for machine fill.
__global__ __launch_bounds__(1024) void kbinA(const int* __restrict__ ei,
                                              const float* __restrict__ ew,
                                              int* gcntD, int* gcntS,
                                              uint2* listD, uint2* listS) {
  __shared__ int histD[NBIN], pfxD[NBIN], gbD[NBIN];
  __shared__ int histS[NBIN], pfxS[NBIN], gbS[NBIN];
  __shared__ __align__(16) uint2 stgD[EPB_A];
  __shared__ __align__(16) uint2 stgS[EPB_A];
  int tid = threadIdx.x;
  if (tid < NBIN) { histD[tid] = 0; histS[tid] = 0; }
  __syncthreads();
  int base = blockIdx.x * EPB_A + tid;
  unsigned recw[2]; int dd[2], ss[2], slotD[2], slotS[2]; float wv[2];
  #pragma unroll
  for (int j = 0; j < 2; ++j) {
    int e = base + j * TPB_A;
    if (e < E_) {
      int s = ei[e], d = ei[E_ + e];
      float w = ew[e];
      recw[j] = (unsigned)s | ((unsigned)f2bf(w) << 16);
      wv[j] = w; dd[j] = d; ss[j] = s;
      slotD[j] = atomicAdd(&histD[d >> BIN_SH], 1);  // LDS return-atomic
      slotS[j] = atomicAdd(&histS[s >> BIN_SH], 1);
    } else { dd[j] = -1; ss[j] = -1; }
  }
  __syncthreads();
  if (tid < NBIN) {  // exclusive scan (all-broadcast LDS reads) + global reserve
    int sD = 0, sS = 0;
    for (int j = 0; j < tid; ++j) { sD += histD[j]; sS += histS[j]; }
    pfxD[tid] = sD; pfxS[tid] = sS;
    gbD[tid] = histD[tid] ? atomicAdd(gcntD + tid, histD[tid]) : 0;
    gbS[tid] = histS[tid] ? atomicAdd(gcntS + tid, histS[tid]) : 0;
  }
  __syncthreads();
  // ---- stage both lists
  #pragma unroll
  for (int j = 0; j < 2; ++j)
    if (dd[j] >= 0) {
      stgD[pfxD[dd[j] >> BIN_SH] + slotD[j]] = (uint2){recw[j], (unsigned)dd[j]};
      union { float f; unsigned u; } cv; cv.f = wv[j];
      stgS[pfxS[ss[j] >> BIN_SH] + slotS[j]] = (uint2){(unsigned)ss[j], cv.u};
    }
  __syncthreads();
  // ---- flush both (wave-coalesced; bin from record)
  int tot  = pfxD[NBIN - 1] + histD[NBIN - 1];
  int totS = pfxS[NBIN - 1] + histS[NBIN - 1];
  for (int i = tid; i < tot; i += TPB_A) {
    uint2 r = stgD[i];
    int b = (int)(r.y >> BIN_SH);
    int pos = gbD[b] + (i - pfxD[b]);
    if (pos < CAPD) listD[(size_t)b * CAPD + pos] = r;
  }
  for (int i = tid; i < totS; i += TPB_A) {
    uint2 r = stgS[i];
    int b = (int)(r.x >> BIN_SH);
    int pos = gbS[b] + (i - pfxS[b]);
    if (pos < CAPS) listS[(size_t)b * CAPS + pos] = r;
  }
}

// kaux: three independent jobs merged for concurrency:
//   blocks [0,NBIN):        deg+dinv+xs+xb from src-bin lists (LDS f32 accumulators)
//   blocks [NBIN,2*NBIN):   bucket-CSR fill from dst-bin lists (LDS slot counters)
//   blocks [2*NBIN,+128):   dense-weight prep (Bt/biasM/BtL/biasL)
__global__ __launch_bounds__(1024) void kaux(
    const int* __restrict__ gcntS, const uint2* __restrict__ listS,
    const float* __restrict__ x, float* __restrict__ dinv,
    u16* __restrict__ xs, u16* __restrict__ xb,
    const int* __restrict__ gcntD, const uint2* __restrict__ listD,
    unsigned* __restrict__ bkt, int* __restrict__ cnt,
    const float* __restrict__ Wxz, const float* __restrict__ Wxh,
    const float* __restrict__ bxz, const float* __restrict__ bhz,
    const float* __restrict__ bxh, const float* __restrict__ bhh,
    const float* __restrict__ Wlin, const float* __restrict__ blin,
    u16* __restrict__ Bt, float* __restrict__ biasM,
    u16* __restrict__ BtL, float* __restrict__ biasL) {
  __shared__ int smem[512];
  int b = blockIdx.x, tid = threadIdx.x;
  if (b < NBIN) {
    // ---- deg + dinv + xs (scaled gather input) + xb (plain bf16 feature)
    float* acc = (float*)smem;
    if (tid < 512) acc[tid] = 0.f;
    __syncthreads();
    int m = gcntS[b]; if (m > CAPS) m = CAPS;
    const uint2* lp = listS + (size_t)b * CAPS;
    for (int i = tid; i < m; i += 1024) {
      uint2 r = lp[i];
      union { unsigned u; float f; } cv; cv.u = r.y;
      atomicAdd(&acc[r.x & 511], cv.f);
    }
    __syncthreads();
    float dv = 0.f, sc = 1.f;
    if (tid < 512) {
      float d = acc[tid];
      dv = (d > 0.f) ? rsqrtf(d) : 0.f;
      sc = (d > 0.f) ? dv : 1.0f;
    }
    __syncthreads();
    if (tid < 512) {
      acc[tid] = sc;
      int n = b * 512 + tid;
      if (n < N_) dinv[n] = dv;
    }
    __syncthreads();
    int nbase = b * 512;
    for (int i = tid; i < 8192; i += 1024) {   // 512 nodes x 16 float4
      int nl = i >> 4, q = i & 15;
      int n = nbase + nl;
      if (n >= N_) break;                      // nl monotone per thread
      float4 xv = ((const float4*)x)[(size_t)n * 16 + q];
      float s = acc[nl];
      ushort4 ov = { f2bf(xv.x * s), f2bf(xv.y * s), f2bf(xv.z * s), f2bf(xv.w * s) };
      ((ushort4*)xs)[(size_t)n * 16 + q] = ov;
      ushort4 ob = { f2bf(xv.x), f2bf(xv.y), f2bf(xv.z), f2bf(xv.w) };
      ((ushort4*)xb)[(size_t)n * 16 + q] = ob;
    }
  } else if (b < 2 * NBIN) {
    // ---- bucket-CSR fill (bin's 96KB region stays L2-hot); cnt written coalesced
    int bb = b - NBIN;
    int* lcnt = smem;
    if (tid < 512) lcnt[tid] = 0;
    __syncthreads();
    int m = gcntD[bb]; if (m > CAPD) m = CAPD;
    const uint2* lp = listD + (size_t)bb * CAPD;
    for (int i = tid; i < m; i += 1024) {
      uint2 r = lp[i];
      int node = (int)r.y;
      int s = atomicAdd(&lcnt[node & 511], 1);
      if (s < BKT) bkt[(size_t)node * BKT + s] = r.x;
    }
    __syncthreads();
    int n = bb * 512 + tid;
    if (tid < 512 && n < N_) cnt[n] = lcnt[tid];
  } else {
    // ---- combined dense weights: Bt[n][k], n<64 z-branch else h-branch;
    // k<64 -> W[0]-W[2] (Tx2=2S-x fold), k<128 -> W[1], else 2*W[2].
    int n = b - 2 * NBIN, c = n & 63;
    const float* W = (n < 64) ? Wxz : Wxh;
    if (tid < 192) {
      int k = tid; float v;
      if (k < 64)       v = W[k*64 + c] - W[2*4096 + k*64 + c];
      else if (k < 128) v = W[4096 + (k-64)*64 + c];
      else              v = 2.0f * W[2*4096 + (k-128)*64 + c];
      Bt[n*200 + k] = f2bf(v);
    } else if (tid < 200) Bt[n*200 + tid] = 0;
    if (tid == 0) biasM[n] = (n < 64) ? (bxz[c] + bhz[c]) : (bxh[c] + bhh[c]);
    if (n < 64) {
      if (tid < 64)      BtL[n*72 + tid] = f2bf(Wlin[tid*64 + n]);
      else if (tid < 72) BtL[n*72 + tid] = 0;
      if (tid == 0)      biasL[n] = blin[n];
    }
  }
}

// out[n] = scale(n) * sum_e ew_e * src[s_e]. 8 nodes/wave (8 lanes/node, ushort8=16B loads):
// one feature-load instruction services 8 edges (round 6->7 measured this dial pays);
// records via uint4 every 4th iter. Line traffic unchanged (2 lines/row).
// Pass 1 (dsc!=0): dsc = -dv^2*sum (gather input), dft = -dv*sum (GEMM feature Tx1u).
// Pass 2 (dsc==0): dft = -dv*sum (GEMM feature S).
__global__ __launch_bounds__(256) void kgather(
    const u16* __restrict__ srcp, const int* __restrict__ cnt, const float* __restrict__ dinv,
    const unsigned* __restrict__ bkt, u16* __restrict__ dsc, u16* __restrict__ dft) {
  int n = blockIdx.x * 32 + (threadIdx.x >> 3);
  if (n >= N_) return;
  int li = threadIdx.x & 7;                  // feature octet [li*8, li*8+8)
  int c = cnt[n]; c = (c > BKT) ? BKT : c;
  const unsigned* recs = bkt + (size_t)n * BKT;
  float a0=0.f,a1=0.f,a2=0.f,a3=0.f,a4=0.f,a5=0.f,a6=0.f,a7=0.f;
  float b0=0.f,b1=0.f,b2=0.f,b3=0.f,b4=0.f,b5=0.f,b6=0.f,b7=0.f;
  int j = 0;
  for (; j + 3 < c; j += 4) {
    uint4 rr = *(const uint4*)(recs + j);
    float w0 = bf2f((u16)(rr.x >> 16)), w1 = bf2f((u16)(rr.y >> 16));
    float w2 = bf2f((u16)(rr.z >> 16)), w3 = bf2f((u16)(rr.w >> 16));
    short8 p0 = *(const short8*)(srcp + (size_t)(rr.x & 0xffffu) * 64 + li * 8);
    short8 p1 = *(const short8*)(srcp + (size_t)(rr.y & 0xffffu) * 64 + li * 8);
    short8 p2 = *(const short8*)(srcp + (size_t)(rr.z & 0xffffu) * 64 + li * 8);
    short8 p3 = *(const short8*)(srcp + (size_t)(rr.w & 0xffffu) * 64 + li * 8);
    a0 += w0*bf2f((u16)p0[0]); a1 += w0*bf2f((u16)p0[1]); a2 += w0*bf2f((u16)p0[2]); a3 += w0*bf2f((u16)p0[3]);
    a4 += w0*bf2f((u16)p0[4]); a5 += w0*bf2f((u16)p0[5]); a6 += w0*bf2f((u16)p0[6]); a7 += w0*bf2f((u16)p0[7]);
    b0 += w1*bf2f((u16)p1[0]); b1 += w1*bf2f((u16)p1[1]); b2 += w1*bf2f((u16)p1[2]); b3 += w1*bf2f((u16)p1[3]);
    b4 += w1*bf2f((u16)p1[4]); b5 += w1*bf2f((u16)p1[5]); b6 += w1*bf2f((u16)p1[6]); b7 += w1*bf2f((u16)p1[7]);
    a0 += w2*bf2f((u16)p2[0]); a1 += w2*bf2f((u16)p2[1]); a2 += w2*bf2f((u16)p2[2]); a3 += w2*bf2f((u16)p2[3]);
    a4 += w2*bf2f((u16)p2[4]); a5 += w2*bf2f((u16)p2[5]); a6 += w2*bf2f((u16)p2[6]); a7 += w2*bf2f((u16)p2[7]);
    b0 += w3*bf2f((u16)p3[0]); b1 += w3*bf2f((u16)p3[1]); b2 += w3*bf2f((u16)p3[2]); b3 += w3*bf2f((u16)p3[3]);
    b4 += w3*bf2f((u16)p3[4]); b5 += w3*bf2f((u16)p3[5]); b6 += w3*bf2f((u16)p3[6]); b7 += w3*bf2f((u16)p3[7]);
  }
  for (; j < c; ++j) {
    unsigned r0 = recs[j];
    float w0 = bf2f((u16)(r0 >> 16));
    short8 p0 = *(const short8*)(srcp + (size_t)(r0 & 0xffffu) * 64 + li * 8);
    a0 += w0*bf2f((u16)p0[0]); a1 += w0*bf2f((u16)p0[1]); a2 += w0*bf2f((u16)p0[2]); a3 += w0*bf2f((u16)p0[3]);
    a4 += w0*bf2f((u16)p0[4]); a5 += w0*bf2f((u16)p0[5]); a6 += w0*bf2f((u16)p0[6]); a7 += w0*bf2f((u16)p0[7]);
  }
  a0 += b0; a1 += b1; a2 += b2; a3 += b3; a4 += b4; a5 += b5; a6 += b6; a7 += b7;
  float dv = dinv[n];
  float sf = -dv;                            // feature scale
  ushort4 f0 = { f2bf(a0*sf), f2bf(a1*sf), f2bf(a2*sf), f2bf(a3*sf) };
  ushort4 f1 = { f2bf(a4*sf), f2bf(a5*sf), f2bf(a6*sf), f2bf(a7*sf) };
  *(ushort4*)(dft + (size_t)n * 64 + li * 8)     = f0;
  *(ushort4*)(dft + (size_t)n * 64 + li * 8 + 4) = f1;
  if (dsc) {
    float ss = -dv * dv;                     // gather-input scale
    ushort4 s0 = { f2bf(a0*ss), f2bf(a1*ss), f2bf(a2*ss), f2bf(a3*ss) };
    ushort4 s1 = { f2bf(a4*ss), f2bf(a5*ss), f2bf(a6*ss), f2bf(a7*ss) };
    *(ushort4*)(dsc + (size_t)n * 64 + li * 8)     = s0;
    *(ushort4*)(dsc + (size_t)n * 64 + li * 8 + 4) = s1;
  }
}

// Pure dense: 128 rows/block. [128x192]@[192x128] -> gate -> [128x64]@[64x64] -> out.
// mfma_f32_16x16x32_bf16: A[m=lane&15][k=quad*8+j], B[k][n=lane&15], D col=lane&15,row=quad*4+reg
// Features xb (=x), Tx1u (=-dinv*G1), Sb (=-dinv*G2) pre-materialized unscaled.
__global__ __launch_bounds__(256) void kgemm(
    const u16* __restrict__ xb, const u16* __restrict__ Tx1u, const u16* __restrict__ Sb,
    const u16* __restrict__ Bt, const float* __restrict__ biasM,
    const u16* __restrict__ BtL, const float* __restrict__ biasL,
    float* __restrict__ out) {
  __shared__ __align__(16) u16 sBt[25600];  // phase1: Bt 128x200 (51200B); phase2: H 128x72 @0 | BtL @9216
  int tid = threadIdx.x, wave = tid >> 6, lane = tid & 63;
  int m16 = lane & 15, quad = lane >> 4;
  int row_base = blockIdx.x * 128;

  for (int i = tid; i < 3200; i += 256)
    ((uint4*)sBt)[i] = ((const uint4*)Bt)[i];

  short8 a[2][6];
  #pragma unroll
  for (int h = 0; h < 2; ++h) {
    int r = row_base + (wave * 2 + h) * 16 + m16;
    if (r < N_) {
      const u16* xr = xb   + (size_t)r * 64;
      const u16* tr = Tx1u + (size_t)r * 64;
      const u16* sr = Sb   + (size_t)r * 64;
      a[h][0] = *(const short8*)(xr + quad * 8);
      a[h][1] = *(const short8*)(xr + 32 + quad * 8);
      a[h][2] = *(const short8*)(tr + quad * 8);
      a[h][3] = *(const short8*)(tr + 32 + quad * 8);
      a[h][4] = *(const short8*)(sr + quad * 8);
      a[h][5] = *(const short8*)(sr + 32 + quad * 8);
    } else {
      short8 z = {0,0,0,0,0,0,0,0};
      #pragma unroll
      for (int s = 0; s < 6; ++s) a[h][s] = z;
    }
  }
  __syncthreads();

  f32x4 acc[2][8];
  #pragma unroll
  for (int h = 0; h < 2; ++h)
    #pragma unroll
    for (int t = 0; t < 8; ++t) acc[h][t] = (f32x4){0.f, 0.f, 0.f, 0.f};
  #pragma unroll
  for (int t = 0; t < 8; ++t) {
    const u16* brow = sBt + (t * 16 + m16) * 200;
    #pragma unroll
    for (int s = 0; s < 6; ++s) {
      short8 b = *(const short8*)(brow + s * 32 + quad * 8);
      acc[0][t] = __builtin_amdgcn_mfma_f32_16x16x32_bf16(a[0][s], b, acc[0][t], 0, 0, 0);
      acc[1][t] = __builtin_amdgcn_mfma_f32_16x16x32_bf16(a[1][s], b, acc[1][t], 0, 0, 0);
    }
  }
  __syncthreads();

  // gate: H = relu( tanh(hpre) * (1 - sigmoid(zpre)) ) -> bf16 rows @ sBt, stride 72
  #pragma unroll
  for (int h = 0; h < 2; ++h) {
    #pragma unroll
    for (int t = 0; t < 4; ++t) {
      int c = t * 16 + m16;
      float bz = biasM[c], bh = biasM[64 + c];
      #pragma unroll
      for (int rr = 0; rr < 4; ++rr) {
        float z  = acc[h][t][rr] + bz;
        float hp = acc[h][t + 4][rr] + bh;
        float th = 1.0f - 2.0f / (__expf(2.0f * hp) + 1.0f);
        float hv = th / (1.0f + __expf(z));
        hv = fmaxf(hv, 0.0f);
        sBt[((wave * 2 + h) * 16 + quad * 4 + rr) * 72 + c] = f2bf(hv);
      }
    }
  }
  for (int i = tid; i < 576; i += 256)
    ((uint4*)(sBt + 9216))[i] = ((const uint4*)BtL)[i];
  __syncthreads();

  short8 a2[2][2];
  #pragma unroll
  for (int h = 0; h < 2; ++h) {
    const u16* hrow = sBt + ((wave * 2 + h) * 16 + m16) * 72;
    a2[h][0] = *(const short8*)(hrow + quad * 8);
    a2[h][1] = *(const short8*)(hrow + 32 + quad * 8);
  }
  f32x4 acc2[2][4];
  #pragma unroll
  for (int h = 0; h < 2; ++h)
    #pragma unroll
    for (int t = 0; t < 4; ++t) acc2[h][t] = (f32x4){0.f, 0.f, 0.f, 0.f};
  #pragma unroll
  for (int t = 0; t < 4; ++t) {
    const u16* brow = sBt + 9216 + (t * 16 + m16) * 72;
    short8 b0 = *(const short8*)(brow + quad * 8);
    short8 b1 = *(const short8*)(brow + 32 + quad * 8);
    #pragma unroll
    for (int h = 0; h < 2; ++h) {
      acc2[h][t] = __builtin_amdgcn_mfma_f32_16x16x32_bf16(a2[h][0], b0, acc2[h][t], 0, 0, 0);
      acc2[h][t] = __builtin_amdgcn_mfma_f32_16x16x32_bf16(a2[h][1], b1, acc2[h][t], 0, 0, 0);
    }
  }
  #pragma unroll
  for (int h = 0; h < 2; ++h) {
    #pragma unroll
    for (int t = 0; t < 4; ++t) {
      int c = t * 16 + m16;
      float bl = biasL[c];
      #pragma unroll
      for (int rr = 0; rr < 4; ++rr) {
        int nr = row_base + (wave * 2 + h) * 16 + quad * 4 + rr;
        if (nr < N_) out[(size_t)nr * 64 + c] = acc2[h][t][rr] + bl;
      }
    }
  }
}

extern "C" void kernel_launch(void* const* d_in, const int* in_sizes, int n_in,
                              void* d_out, int out_size, void* d_ws, size_t ws_size,
                              hipStream_t stream) {
  const float* x    = (const float*)d_in[0];
  const int*   ei   = (const int*)d_in[1];
  const float* ew   = (const float*)d_in[2];
  const float* Wxz  = (const float*)d_in[3];
  const float* bxz  = (const float*)d_in[4];
  const float* bhz  = (const float*)d_in[6];
  const float* Wxh  = (const float*)d_in[11];
  const float* bxh  = (const float*)d_in[12];
  const float* bhh  = (const float*)d_in[14];
  const float* Wlin = (const float*)d_in[15];
  const float* blin = (const float*)d_in[16];
  float* out = (float*)d_out;

  char* ws = (char*)d_ws;
  float*    dinv  = (float*)   (ws + B_DINV);
  int*      cnt   = (int*)     (ws + B_CNT);
  unsigned* bkt   = (unsigned*)(ws + B_BKT);
  u16*      xsb   = (u16*)     (ws + B_XS);
  u16*      Tx1s  = (u16*)     (ws + B_TX1S);
  u16*      Sb    = (u16*)     (ws + B_S);
  uint2*    listD = (uint2*)   (ws + B_LISTD);
  uint2*    listS = (uint2*)   (ws + B_LISTS);
  int*      gcntD = (int*)     (ws + B_GCNTD);
  int*      gcntS = (int*)     (ws + B_GCNTS);
  u16*      Bt    = (u16*)     (ws + B_BT);
  float*    biasM = (float*)   (ws + B_BIASM);
  u16*      BtL   = (u16*)     (ws + B_BTL);
  float*    biasL = (float*)   (ws + B_BIASL);
  u16*      xbb   = (u16*)     (ws + B_XB);
  u16*      Tx1u  = (u16*)     (ws + B_TX1U);

  hipMemsetAsync(ws + B_GCNTD, 0, 1024, stream);   // gcntD + gcntS (contiguous)
  kbinA  <<<(E_ + EPB_A - 1) / EPB_A, TPB_A, 0, stream>>>(ei, ew, gcntD, gcntS, listD, listS);
  kaux   <<<GAUX, 1024, 0, stream>>>(gcntS, listS, x, dinv, xsb, xbb,
                                     gcntD, listD, bkt, cnt,
                                     Wxz, Wxh, bxz, bhz, bxh, bhh, Wlin, blin,
                                     Bt, biasM, BtL, biasL);
  kgather<<<(N_ + 31) / 32, 256, 0, stream>>>(xsb,  cnt, dinv, bkt, Tx1s, Tx1u); // pass 1
  kgather<<<(N_ + 31) / 32, 256, 0, stream>>>(Tx1s, cnt, dinv, bkt, 0,    Sb);   // pass 2
  kgemm  <<<(N_ + 127) / 128, 256, 0, stream>>>(xbb, Tx1u, Sb, Bt, biasM, BtL, biasL, out);
}